// Round 2
// baseline (776.767 us; speedup 1.0000x reference)
//
#include <hip/hip_runtime.h>
#include <math.h>

#define B_ 2
#define L_ 2048
#define E_ 1024
#define N_ 16
#define R_ 64
#define PW 96          // R_ + 2*N_
#define BL_ (B_*L_)    // 4096

__device__ __forceinline__ float softplusf(float x) {
    return fmaxf(x, 0.0f) + log1pf(expf(-fabsf(x)));
}
__device__ __forceinline__ float siluf(float x) {
    return x / (1.0f + expf(-x));
}

// C = X(M x Kd) * W(N x Kd)^T
// XT=0: X row-major [M, Kd], row stride ldx.
// XT=1: X stored K-major per batch: element (k, m) at X[(b*Kd + k)*Ld + (m - b*Ld)],
//       b = m/Ld  (requires BM | Ld so tiles don't cross batch).
// MODE 0: C[m*N + n] = v
// MODE 1: transposed store C[b*N*Ld + n*Ld + (m-b*Ld)]   (LDS-staged, coalesced)
// MODE 2: like 1, with v = softplus(v + bias[n])
template<int BM, int BN, int BK, int TM, int TN, int MODE, int XT>
__global__ __launch_bounds__((BM/TM)*(BN/TN))
void gemm_xwt(const float* __restrict__ X, const float* __restrict__ W,
              const float* __restrict__ bias, float* __restrict__ C,
              int M, int N, int Kd, int ldx, int Ld) {
    constexpr int NT = (BM/TM)*(BN/TN);
    constexpr int TCOLS = BN/TN;
    static_assert(MODE == 0 || (BM == 128 && BN == 128), "transpose epilogue assumes 128x128");
    __shared__ float Xs[BK][BM+8];               // +8: rows 16B-aligned (544B stride)
    __shared__ float Ws[BK][BN+4];
    __shared__ float Ts[(MODE != 0) ? 32 : 1][BM+4];   // transpose staging (528B stride, 16B-aligned)
    const int tid = threadIdx.x;
    const int m0 = blockIdx.x * BM;
    const int n0 = blockIdx.y * BN;
    const int tr = tid / TCOLS;
    const int tc = tid % TCOLS;

    float acc[TM][TN];
#pragma unroll
    for (int i = 0; i < TM; ++i)
#pragma unroll
        for (int j = 0; j < TN; ++j) acc[i][j] = 0.0f;

    const int bb = m0 / Ld;                      // batch index of this m-tile
    for (int kt = 0; kt < Kd; kt += BK) {
        if constexpr (XT) {
            const float* Xbase = X + (size_t)bb*Kd*Ld + (m0 - bb*Ld);
            for (int i = tid; i < (BM*BK)/4; i += NT) {
                const int idx = i * 4;
                const int kk = idx / BM, r = idx % BM;
                float4 v = *reinterpret_cast<const float4*>(Xbase + (size_t)(kt+kk)*Ld + r);
                *reinterpret_cast<float4*>(&Xs[kk][r]) = v;
            }
        } else {
            for (int i = tid; i < (BM*BK)/4; i += NT) {
                const int idx = i * 4;
                const int r = idx / BK, kk = idx % BK;
                const int gm = m0 + r;
                float4 v = make_float4(0.f, 0.f, 0.f, 0.f);
                if (gm < M) v = *reinterpret_cast<const float4*>(X + (size_t)gm*ldx + kt + kk);
                Xs[kk+0][r] = v.x; Xs[kk+1][r] = v.y; Xs[kk+2][r] = v.z; Xs[kk+3][r] = v.w;
            }
        }
        for (int i = tid; i < (BN*BK)/4; i += NT) {
            const int idx = i * 4;
            const int r = idx / BK, kk = idx % BK;
            const int gn = n0 + r;
            float4 v = make_float4(0.f, 0.f, 0.f, 0.f);
            if (gn < N) v = *reinterpret_cast<const float4*>(W + (size_t)gn*Kd + kt + kk);
            Ws[kk+0][r] = v.x; Ws[kk+1][r] = v.y; Ws[kk+2][r] = v.z; Ws[kk+3][r] = v.w;
        }
        __syncthreads();
#pragma unroll
        for (int kk = 0; kk < BK; ++kk) {
            float a[TM], bbv[TN];
#pragma unroll
            for (int i = 0; i < TM; ++i) a[i] = Xs[kk][tr*TM + i];
#pragma unroll
            for (int j = 0; j < TN; ++j) bbv[j] = Ws[kk][tc*TN + j];
#pragma unroll
            for (int i = 0; i < TM; ++i)
#pragma unroll
                for (int j = 0; j < TN; ++j)
                    acc[i][j] = fmaf(a[i], bbv[j], acc[i][j]);
        }
        __syncthreads();
    }

    if constexpr (MODE == 0) {
#pragma unroll
        for (int i = 0; i < TM; ++i) {
            const int m = m0 + tr*TM + i;
            if (m >= M) continue;
#pragma unroll
            for (int j = 0; j < TN; ++j) {
                const int n = n0 + tc*TN + j;
                if (n >= N) continue;
                C[(size_t)m*N + n] = acc[i][j];
            }
        }
    } else {
        // LDS-staged transpose: emit C[b][n][m%Ld] with float4 stores along m (the L dim).
        float* Cbase = C + (size_t)bb*N*Ld + (m0 - bb*Ld);
#pragma unroll
        for (int nc = 0; nc < BN/32; ++nc) {
            if (tc >= nc*4 && tc < nc*4 + 4) {
#pragma unroll
                for (int j = 0; j < TN; ++j) {
                    const int nl = tc*TN + j - nc*32;       // 0..31
#pragma unroll
                    for (int i = 0; i < TM; ++i) {
                        float v = acc[i][j];
                        if constexpr (MODE == 2) v = softplusf(v + bias[n0 + tc*TN + j]);
                        Ts[nl][tr*TM + i] = v;
                    }
                }
            }
            __syncthreads();
            for (int idx = tid; idx < 32*(BM/4); idx += NT) {
                const int row = idx / (BM/4);
                const int c4  = idx % (BM/4);
                float4 v = *reinterpret_cast<float4*>(&Ts[row][c4*4]);
                *reinterpret_cast<float4*>(Cbase + (size_t)(n0 + nc*32 + row)*Ld + c4*4) = v;
            }
            __syncthreads();
        }
    }
}

// depthwise causal conv (K=4) + silu; x is [b,l,e] -> uT[b,e,l], LDS-transposed.
// grid: (E/64, L/64, B), block: 256
__global__ __launch_bounds__(256)
void conv_silu_kernel(const float* __restrict__ x, const float* __restrict__ cw,
                      float* __restrict__ uT) {
    __shared__ float Xt[67][65];                 // rows: l0-3 .. l0+63, cols: e, padded
    const int e0 = blockIdx.x * 64;
    const int l0 = blockIdx.y * 64;
    const int b  = blockIdx.z;
    const int tid = threadIdx.x;

    for (int idx = tid; idx < 67*64; idx += 256) {
        const int row = idx >> 6, col = idx & 63;
        const int gl = l0 - 3 + row;
        Xt[row][col] = (gl >= 0) ? x[((size_t)b*L_ + gl)*E_ + e0 + col] : 0.0f;
    }
    __syncthreads();

    const int lL = tid & 63;
    const int w  = tid >> 6;                     // wave id 0..3
    for (int ee = w; ee < 64; ee += 4) {
        const int e = e0 + ee;
        const float w0 = cw[e*4+0], w1 = cw[e*4+1], w2 = cw[e*4+2], w3 = cw[e*4+3];
        const float v = w0*Xt[lL][ee] + w1*Xt[lL+1][ee] + w2*Xt[lL+2][ee] + w3*Xt[lL+3][ee];
        uT[((size_t)b*E_ + e)*L_ + l0 + lL] = siluf(v);
    }
}

// selective scan: one wave per (b,e) channel. Chunked parallel scan over L.
// Reference recurrence (shifted): H_0 = g_0;  H_{l+1} = a_l H_l + g_l
// where a_l[n] = exp(dt_l*A[n]), g_l[n] = bt_l[n]*u_l. Output at l uses H_l.
__global__ __launch_bounds__(64)
void scan_kernel(const float* __restrict__ dtT, const float* __restrict__ uT,
                 const float* __restrict__ zT, const float* __restrict__ params,
                 const float* __restrict__ A_log, const float* __restrict__ Dp,
                 float* __restrict__ ygT) {
    const int c = blockIdx.x;
    const int b = c >> 10;        // /E_
    const int e = c & (E_-1);
    const int lane = threadIdx.x;
    constexpr int CH = L_/64;     // 32 timesteps per lane

    float An[N_];
#pragma unroll
    for (int n = 0; n < N_; ++n) An[n] = -expf(A_log[e*N_ + n]);
    const float Dv = Dp[e];

    const float* dtp = dtT + ((size_t)b*E_ + e)*L_;
    const float* up  = uT  + ((size_t)b*E_ + e)*L_;
    const float* zp  = zT  + ((size_t)b*E_ + e)*L_;
    const int l0 = lane * CH;

    // ---- pass 1: per-chunk linear transform T_i(x) = P*x + Lc ----
    float P[N_], h[N_];
#pragma unroll
    for (int n = 0; n < N_; ++n) { P[n] = 1.0f; h[n] = 0.0f; }
    for (int j4 = 0; j4 < CH; j4 += 4) {
        float d4[4], u4[4];
        *reinterpret_cast<float4*>(d4) = *reinterpret_cast<const float4*>(dtp + l0 + j4);
        *reinterpret_cast<float4*>(u4) = *reinterpret_cast<const float4*>(up  + l0 + j4);
#pragma unroll
        for (int q = 0; q < 4; ++q) {
            const float d = d4[q], uu = u4[q];
#pragma unroll
            for (int n = 0; n < N_; ++n) {
                const float at = expf(d * An[n]);
                const float bt = (fabsf(An[n]) < 1e-5f) ? d : (at - 1.0f) / (An[n] + 1e-10f);
                h[n] = fmaf(at, h[n], bt * uu);
                P[n] *= at;
            }
        }
    }

    // ---- inclusive wave scan of transforms ----
#pragma unroll
    for (int off = 1; off < 64; off <<= 1) {
#pragma unroll
        for (int n = 0; n < N_; ++n) {
            const float Pp = __shfl_up(P[n], off);
            const float Lp = __shfl_up(h[n], off);
            if (lane >= off) {
                h[n] = fmaf(P[n], Lp, h[n]);
                P[n] *= Pp;
            }
        }
    }

    // carry from previous lane
    float cP[N_], cL[N_];
#pragma unroll
    for (int n = 0; n < N_; ++n) {
        cP[n] = __shfl_up(P[n], 1);
        cL[n] = __shfl_up(h[n], 1);
    }

    // seed: H_0 = g_0
    const float d0 = dtp[0];
    const float u0 = up[0];
#pragma unroll
    for (int n = 0; n < N_; ++n) {
        const float at0 = expf(d0 * An[n]);
        const float bt0 = (fabsf(An[n]) < 1e-5f) ? d0 : (at0 - 1.0f) / (An[n] + 1e-10f);
        const float g0 = bt0 * u0;
        h[n] = (lane == 0) ? g0 : fmaf(cP[n], g0, cL[n]);   // H at chunk start
    }

    // ---- pass 2: emit outputs (coalesced along l), then update state ----
    const float* crow = params + (size_t)b*L_*PW + 80;      // C_proj columns [80,96)
    float* yp = ygT + ((size_t)b*E_ + e)*L_;
    for (int j4 = 0; j4 < CH; j4 += 4) {
        const int l = l0 + j4;
        float d4[4], u4[4], z4[4], ov[4];
        *reinterpret_cast<float4*>(d4) = *reinterpret_cast<const float4*>(dtp + l);
        *reinterpret_cast<float4*>(u4) = *reinterpret_cast<const float4*>(up  + l);
        *reinterpret_cast<float4*>(z4) = *reinterpret_cast<const float4*>(zp  + l);
#pragma unroll
        for (int q = 0; q < 4; ++q) {
            const float d = d4[q], uu = u4[q];
            float Cv[N_];
            const float4* Cp4 = reinterpret_cast<const float4*>(crow + (size_t)(l+q)*PW);
#pragma unroll
            for (int t = 0; t < N_/4; ++t)
                *reinterpret_cast<float4*>(Cv + t*4) = Cp4[t];
            float y = 0.0f;
#pragma unroll
            for (int n = 0; n < N_; ++n) y = fmaf(Cv[n], h[n], y);
            ov[q] = (y + uu * Dv) * siluf(z4[q]);
#pragma unroll
            for (int n = 0; n < N_; ++n) {
                const float at = expf(d * An[n]);
                const float bt = (fabsf(An[n]) < 1e-5f) ? d : (at - 1.0f) / (An[n] + 1e-10f);
                h[n] = fmaf(at, h[n], bt * uu);
            }
        }
        *reinterpret_cast<float4*>(yp + l) = *reinterpret_cast<float4*>(ov);
    }
}

extern "C" void kernel_launch(void* const* d_in, const int* in_sizes, int n_in,
                              void* d_out, int out_size, void* d_ws, size_t ws_size,
                              hipStream_t stream) {
    const float* x     = (const float*)d_in[0];
    const float* W_z   = (const float*)d_in[1];
    const float* W_p   = (const float*)d_in[2];
    const float* cw    = (const float*)d_in[3];
    const float* W_dt  = (const float*)d_in[4];
    const float* b_dt  = (const float*)d_in[5];
    const float* A_log = (const float*)d_in[6];
    const float* Dp    = (const float*)d_in[7];
    const float* W_out = (const float*)d_in[8];
    float* out = (float*)d_out;

    float* ws     = (float*)d_ws;
    float* zT     = ws;                         // B*E*L
    float* params = zT + (size_t)B_*E_*L_;      // BL*96
    float* dtT    = params + (size_t)BL_*PW;    // B*E*L
    float* uT     = dtT + (size_t)B_*E_*L_;     // B*E*L
    float* ygT    = uT + (size_t)B_*E_*L_;      // B*E*L

    // z = x @ W_z^T  -> zT[b,e,l]
    gemm_xwt<128,128,16,8,8,1,0><<<dim3(BL_/128, E_/128), 256, 0, stream>>>(
        x, W_z, nullptr, zT, BL_, E_, E_, E_, L_);
    // params = x @ W_params^T  -> [bl,96]
    gemm_xwt<64,32,16,4,2,0,0><<<dim3(BL_/64, 3), 256, 0, stream>>>(
        x, W_p, nullptr, params, BL_, PW, E_, E_, L_);
    // dt = softplus(params[:, :64] @ W_dt^T + b_dt) -> dtT[b,e,l]
    gemm_xwt<128,128,8,8,8,2,0><<<dim3(BL_/128, E_/128), 256, 0, stream>>>(
        params, W_dt, b_dt, dtT, BL_, E_, R_, PW, L_);
    // depthwise causal conv + silu -> uT[b,e,l]
    conv_silu_kernel<<<dim3(E_/64, L_/64, B_), 256, 0, stream>>>(x, cw, uT);
    // selective scan + gating -> ygT[b,e,l]
    scan_kernel<<<B_*E_, 64, 0, stream>>>(dtT, uT, zT, params, A_log, Dp, ygT);
    // out = yg @ W_out^T   (A read from ygT via XT path)
    gemm_xwt<128,128,16,8,8,0,1><<<dim3(BL_/128, E_/128), 256, 0, stream>>>(
        ygT, W_out, nullptr, out, BL_, E_, E_, L_, L_);
}

// Round 3
// 503.559 us; speedup vs baseline: 1.5426x; 1.5426x over previous
//
#include <hip/hip_runtime.h>
#include <math.h>

#define B_ 2
#define L_ 2048
#define E_ 1024
#define N_ 16
#define R_ 64
#define PWP 128        // padded params pitch (96 -> 128)
#define BL_ (B_*L_)    // 4096

using bf16x8 = __attribute__((ext_vector_type(8))) short;
using f32x4  = __attribute__((ext_vector_type(4))) float;

__device__ __forceinline__ float softplusf(float x) {
    return fmaxf(x, 0.0f) + log1pf(expf(-fabsf(x)));
}
__device__ __forceinline__ float siluf(float x) {
    return x / (1.0f + expf(-x));
}
__device__ __forceinline__ ushort f2bf(float f) {   // RNE float->bf16 (finite data)
    unsigned u = __float_as_uint(f);
    return (ushort)((u + 0x7fffu + ((u >> 16) & 1u)) >> 16);
}
__device__ __forceinline__ float bf2f(ushort h) {
    return __uint_as_float(((unsigned)h) << 16);
}
__device__ __forceinline__ void gload16(const ushort* g, ushort* l) {
    __builtin_amdgcn_global_load_lds((const __attribute__((address_space(1))) void*)g,
                                     (__attribute__((address_space(3))) void*)l, 16, 0, 0);
}

// src fp32 [rows_src][spitch] -> dst [rows_dst][2K] bf16 as [hi(K) | lo(K)]; pad rows zero.
__global__ __launch_bounds__(256)
void split_rm(const float* __restrict__ src, int spitch, int rows_src,
              ushort* __restrict__ dst, int K, int total4) {
    const int idx = blockIdx.x * 256 + threadIdx.x;
    if (idx >= total4) return;
    const int Kq = K >> 2;
    const int r  = idx / Kq;
    const int c4 = (idx - r * Kq) << 2;
    float f[4] = {0.f, 0.f, 0.f, 0.f};
    if (r < rows_src)
        *reinterpret_cast<float4*>(f) = *reinterpret_cast<const float4*>(src + (size_t)r * spitch + c4);
    ushort h[4], lo[4];
#pragma unroll
    for (int q = 0; q < 4; ++q) {
        h[q]  = f2bf(f[q]);
        lo[q] = f2bf(f[q] - bf2f(h[q]));
    }
    ushort* d0 = dst + (size_t)r * 2 * K + c4;
    *reinterpret_cast<uint2*>(d0)     = make_uint2((uint)h[0]  | ((uint)h[1]  << 16), (uint)h[2]  | ((uint)h[3]  << 16));
    *reinterpret_cast<uint2*>(d0 + K) = make_uint2((uint)lo[0] | ((uint)lo[1] << 16), (uint)lo[2] | ((uint)lo[3] << 16));
}

// ygT[b][e][l] fp32 -> Ycat [b*L+l][2E] bf16 hi|lo (LDS transpose, both sides coalesced)
__global__ __launch_bounds__(256)
void split_tr(const float* __restrict__ ygT, ushort* __restrict__ Ycat) {
    __shared__ float Ts[64][65];
    const int e0 = blockIdx.x * 64;
    const int l0 = blockIdx.y * 64;
    const int b  = blockIdx.z;
    const int tid = threadIdx.x;
    for (int idx = tid; idx < 64 * 64; idx += 256) {
        const int rr = idx >> 6, cc = idx & 63;
        Ts[rr][cc] = ygT[((size_t)(b * E_ + e0 + rr) << 11) + l0 + cc];
    }
    __syncthreads();
    for (int idx = tid; idx < 64 * 16; idx += 256) {
        const int rl = idx >> 4, g = idx & 15;
        ushort h[4], lo[4];
#pragma unroll
        for (int q = 0; q < 4; ++q) {
            const float f = Ts[g * 4 + q][rl];
            h[q]  = f2bf(f);
            lo[q] = f2bf(f - bf2f(h[q]));
        }
        ushort* d0 = Ycat + (size_t)(b * L_ + l0 + rl) * 2 * E_ + e0 + g * 4;
        *reinterpret_cast<uint2*>(d0)      = make_uint2((uint)h[0]  | ((uint)h[1]  << 16), (uint)h[2]  | ((uint)h[3]  << 16));
        *reinterpret_cast<uint2*>(d0 + E_) = make_uint2((uint)lo[0] | ((uint)lo[1] << 16), (uint)lo[2] | ((uint)lo[3] << 16));
    }
}

// Split-bf16 MFMA GEMM: D = A * B^T over hi|lo buffers (pitch 2*Kd each).
// Effective K = 3*Kd via segments: A reads (hi,hi,lo), B reads (hi,lo,hi)
//   -> accumulates Ahi*Bhi + Ahi*Blo + Alo*Bhi in fp32 (fp32-class precision).
// Tile 128x128, 4 waves 2x2, wave-tile 64x64 = 4x4 frags of 16x16x32.
// grid.x = Arows/128, grid.y = Brows/128.
// MODE 0: C[m*Ncols + n] (m = A-row, n = B-row)
// MODE 1: A-rows are E (e), B-rows are B*L (b,l): store C[((b*E+e)<<11) + l]
// MODE 2: like 1 with v = softplus(v + bias[e])
template<int MODE>
__global__ __launch_bounds__(256)
void mfma_gemm(const ushort* __restrict__ A, const ushort* __restrict__ Bm,
               const float* __restrict__ bias, float* __restrict__ C,
               int Kd, int Ncols) {
    __shared__ ushort As[128 * 32];
    __shared__ ushort Bs[128 * 32];
    const int tid  = threadIdx.x;
    const int wave = tid >> 6, lane = tid & 63;
    const int m0 = blockIdx.x * 128, n0 = blockIdx.y * 128;
    const int wr = wave >> 1, wc = wave & 1;
    const int fr = lane & 15, fg = lane >> 4;
    const int pK = 2 * Kd;                  // buffer pitch
    const int K32 = Kd >> 5;

    f32x4 acc[4][4];
#pragma unroll
    for (int i = 0; i < 4; ++i)
#pragma unroll
        for (int j = 0; j < 4; ++j) { f32x4 z = {0.f, 0.f, 0.f, 0.f}; acc[i][j] = z; }

    // staging: per wave two 1KB chunks; LDS dest = wave-uniform base + lane*16
    const int srow0 = wave * 32 + (lane >> 2);
    const int srow1 = srow0 + 16;
    const int ske   = (lane & 3) * 8;

    const int T = 3 * K32;
    for (int t = 0; t < T; ++t) {
        int ka, kb;
        if (t < K32)        { ka = t * 32;              kb = t * 32; }
        else if (t < 2*K32) { ka = (t - K32) * 32;      kb = Kd + (t - K32) * 32; }
        else                { ka = Kd + (t - 2*K32)*32; kb = (t - 2*K32) * 32; }

        gload16(A  + (size_t)(m0 + srow0) * pK + ka + ske, As + srow0 * 32 + ske);
        gload16(A  + (size_t)(m0 + srow1) * pK + ka + ske, As + srow1 * 32 + ske);
        gload16(Bm + (size_t)(n0 + srow0) * pK + kb + ske, Bs + srow0 * 32 + ske);
        gload16(Bm + (size_t)(n0 + srow1) * pK + kb + ske, Bs + srow1 * 32 + ske);
        __syncthreads();

        bf16x8 av[4], bv[4];
#pragma unroll
        for (int i = 0; i < 4; ++i)
            av[i] = *reinterpret_cast<const bf16x8*>(&As[(wr * 64 + i * 16 + fr) * 32 + fg * 8]);
#pragma unroll
        for (int j = 0; j < 4; ++j)
            bv[j] = *reinterpret_cast<const bf16x8*>(&Bs[(wc * 64 + j * 16 + fr) * 32 + fg * 8]);
#pragma unroll
        for (int i = 0; i < 4; ++i)
#pragma unroll
            for (int j = 0; j < 4; ++j)
                acc[i][j] = __builtin_amdgcn_mfma_f32_16x16x32_bf16(av[i], bv[j], acc[i][j], 0, 0, 0);
        __syncthreads();
    }

    if constexpr (MODE == 0) {
#pragma unroll
        for (int i = 0; i < 4; ++i) {
            const int m = m0 + wr * 64 + i * 16 + fg * 4;
#pragma unroll
            for (int j = 0; j < 4; ++j) {
                const int n = n0 + wc * 64 + j * 16 + fr;
#pragma unroll
                for (int r = 0; r < 4; ++r)
                    C[(size_t)(m + r) * Ncols + n] = acc[i][j][r];
            }
        }
    } else {
        const int b  = n0 >> 11;            // L_ = 2048
        const int lb = n0 - (b << 11);
#pragma unroll
        for (int i = 0; i < 4; ++i) {
            const int e = m0 + wr * 64 + i * 16 + fg * 4;
#pragma unroll
            for (int r = 0; r < 4; ++r) {
                const float bia = (MODE == 2) ? bias[e + r] : 0.0f;
                float* row = C + ((size_t)(b * E_ + e + r) << 11) + lb;
#pragma unroll
                for (int j = 0; j < 4; ++j) {
                    float v = acc[i][j][r];
                    if constexpr (MODE == 2) v = softplusf(v + bia);
                    row[wc * 64 + j * 16 + fr] = v;
                }
            }
        }
    }
}

// depthwise causal conv (K=4) + silu; x [b,l,e] -> uT[b,e,l]
__global__ __launch_bounds__(256)
void conv_silu_kernel(const float* __restrict__ x, const float* __restrict__ cw,
                      float* __restrict__ uT) {
    __shared__ float Xt[67][65];
    const int e0 = blockIdx.x * 64;
    const int l0 = blockIdx.y * 64;
    const int b  = blockIdx.z;
    const int tid = threadIdx.x;
    for (int idx = tid; idx < 67 * 64; idx += 256) {
        const int row = idx >> 6, col = idx & 63;
        const int gl = l0 - 3 + row;
        Xt[row][col] = (gl >= 0) ? x[((size_t)b * L_ + gl) * E_ + e0 + col] : 0.0f;
    }
    __syncthreads();
    const int lL = tid & 63;
    const int w  = tid >> 6;
    for (int ee = w; ee < 64; ee += 4) {
        const int e = e0 + ee;
        const float w0 = cw[e*4+0], w1 = cw[e*4+1], w2 = cw[e*4+2], w3 = cw[e*4+3];
        const float v = w0*Xt[lL][ee] + w1*Xt[lL+1][ee] + w2*Xt[lL+2][ee] + w3*Xt[lL+3][ee];
        uT[((size_t)b * E_ + e) * L_ + l0 + lL] = siluf(v);
    }
}

// selective scan: one wave per (b,e); chunked parallel scan over L.
// H_0 = g_0; H_{l+1} = a_l H_l + g_l; output at l uses H_l.
__global__ __launch_bounds__(64)
void scan_kernel(const float* __restrict__ dtT, const float* __restrict__ uT,
                 const float* __restrict__ zT, const float* __restrict__ params,
                 const float* __restrict__ A_log, const float* __restrict__ Dp,
                 float* __restrict__ ygT) {
    const int c = blockIdx.x;
    const int b = c >> 10;
    const int e = c & (E_ - 1);
    const int lane = threadIdx.x;
    constexpr int CH = L_ / 64;   // 32

    float An[N_];
#pragma unroll
    for (int n = 0; n < N_; ++n) An[n] = -expf(A_log[e * N_ + n]);
    const float Dv = Dp[e];

    const float* dtp = dtT + ((size_t)b * E_ + e) * L_;
    const float* up  = uT  + ((size_t)b * E_ + e) * L_;
    const float* zp  = zT  + ((size_t)b * E_ + e) * L_;
    const int l0 = lane * CH;

    float P[N_], h[N_];
#pragma unroll
    for (int n = 0; n < N_; ++n) { P[n] = 1.0f; h[n] = 0.0f; }
    for (int j4 = 0; j4 < CH; j4 += 4) {
        float d4[4], u4[4];
        *reinterpret_cast<float4*>(d4) = *reinterpret_cast<const float4*>(dtp + l0 + j4);
        *reinterpret_cast<float4*>(u4) = *reinterpret_cast<const float4*>(up  + l0 + j4);
#pragma unroll
        for (int q = 0; q < 4; ++q) {
            const float d = d4[q], uu = u4[q];
#pragma unroll
            for (int n = 0; n < N_; ++n) {
                const float at = expf(d * An[n]);
                const float bt = (fabsf(An[n]) < 1e-5f) ? d : (at - 1.0f) / (An[n] + 1e-10f);
                h[n] = fmaf(at, h[n], bt * uu);
                P[n] *= at;
            }
        }
    }

#pragma unroll
    for (int off = 1; off < 64; off <<= 1) {
#pragma unroll
        for (int n = 0; n < N_; ++n) {
            const float Pp = __shfl_up(P[n], off);
            const float Lp = __shfl_up(h[n], off);
            if (lane >= off) {
                h[n] = fmaf(P[n], Lp, h[n]);
                P[n] *= Pp;
            }
        }
    }

    float cP[N_], cL[N_];
#pragma unroll
    for (int n = 0; n < N_; ++n) {
        cP[n] = __shfl_up(P[n], 1);
        cL[n] = __shfl_up(h[n], 1);
    }

    const float d0 = dtp[0];
    const float u0 = up[0];
#pragma unroll
    for (int n = 0; n < N_; ++n) {
        const float at0 = expf(d0 * An[n]);
        const float bt0 = (fabsf(An[n]) < 1e-5f) ? d0 : (at0 - 1.0f) / (An[n] + 1e-10f);
        const float g0 = bt0 * u0;
        h[n] = (lane == 0) ? g0 : fmaf(cP[n], g0, cL[n]);
    }

    const float* crow = params + (size_t)b * L_ * PWP + 80;   // C_proj cols [80,96)
    float* yp = ygT + ((size_t)b * E_ + e) * L_;
    for (int j4 = 0; j4 < CH; j4 += 4) {
        const int l = l0 + j4;
        float d4[4], u4[4], z4[4], ov[4];
        *reinterpret_cast<float4*>(d4) = *reinterpret_cast<const float4*>(dtp + l);
        *reinterpret_cast<float4*>(u4) = *reinterpret_cast<const float4*>(up  + l);
        *reinterpret_cast<float4*>(z4) = *reinterpret_cast<const float4*>(zp  + l);
#pragma unroll
        for (int q = 0; q < 4; ++q) {
            const float d = d4[q], uu = u4[q];
            float Cv[N_];
            const float4* Cp4 = reinterpret_cast<const float4*>(crow + (size_t)(l + q) * PWP);
#pragma unroll
            for (int t = 0; t < N_ / 4; ++t)
                *reinterpret_cast<float4*>(Cv + t * 4) = Cp4[t];
            float y = 0.0f;
#pragma unroll
            for (int n = 0; n < N_; ++n) y = fmaf(Cv[n], h[n], y);
            ov[q] = (y + uu * Dv) * siluf(z4[q]);
#pragma unroll
            for (int n = 0; n < N_; ++n) {
                const float at = expf(d * An[n]);
                const float bt = (fabsf(An[n]) < 1e-5f) ? d : (at - 1.0f) / (An[n] + 1e-10f);
                h[n] = fmaf(at, h[n], bt * uu);
            }
        }
        *reinterpret_cast<float4*>(yp + l) = *reinterpret_cast<float4*>(ov);
    }
}

extern "C" void kernel_launch(void* const* d_in, const int* in_sizes, int n_in,
                              void* d_out, int out_size, void* d_ws, size_t ws_size,
                              hipStream_t stream) {
    const float* x     = (const float*)d_in[0];
    const float* W_z   = (const float*)d_in[1];
    const float* W_p   = (const float*)d_in[2];
    const float* cw    = (const float*)d_in[3];
    const float* W_dt  = (const float*)d_in[4];
    const float* b_dt  = (const float*)d_in[5];
    const float* A_log = (const float*)d_in[6];
    const float* Dp    = (const float*)d_in[7];
    const float* W_out = (const float*)d_in[8];
    float* out = (float*)d_out;

    char* w = (char*)d_ws;                       // ~92 MB total
    ushort* Xcat   = (ushort*)(w);               // [4096][2048]  16.78 MB
    ushort* Wzcat  = (ushort*)(w + 16777216);    // [1024][2048]   4.19 MB
    ushort* Wpcat  = (ushort*)(w + 20971520);    // [128][2048]    0.52 MB
    ushort* Wdtcat = (ushort*)(w + 21495808);    // [1024][128]    0.26 MB
    ushort* Pcat   = (ushort*)(w + 21757952);    // [4096][128]    1.05 MB
    float*  params = (float*)(w + 22806528);     // [4096][128]    2.10 MB
    float*  zT     = (float*)(w + 24903680);     // 16.78 MB
    float*  dtT    = (float*)(w + 41680896);     // 16.78 MB
    float*  uT     = (float*)(w + 58458112);     // 16.78 MB
    float*  ygT    = (float*)(w + 75235328);     // 16.78 MB
    ushort* Ycat   = Xcat;                       // alias (Xcat dead by then)
    ushort* Wocat  = Wzcat;                      // alias (Wzcat dead by then)

    // splits
    split_rm<<<4096, 256, 0, stream>>>(x,    E_,  BL_, Xcat,  E_, BL_ * E_ / 4);
    split_rm<<<1024, 256, 0, stream>>>(W_z,  E_,  E_,  Wzcat, E_, E_ * E_ / 4);
    split_rm<<<128,  256, 0, stream>>>(W_p,  E_,  96,  Wpcat, E_, 128 * E_ / 4);
    // z = x @ W_z^T -> zT[b,e,l]   (A = W_z rows e, B = x rows bl)
    mfma_gemm<1><<<dim3(E_ / 128, BL_ / 128), 256, 0, stream>>>(Wzcat, Xcat, nullptr, zT, E_, 0);
    // params = x @ W_p^T -> [bl][128]
    mfma_gemm<0><<<dim3(BL_ / 128, 1), 256, 0, stream>>>(Xcat, Wpcat, nullptr, params, E_, PWP);
    split_rm<<<64,  256, 0, stream>>>(W_dt,   R_,  E_,  Wdtcat, R_, E_ * R_ / 4);
    split_rm<<<256, 256, 0, stream>>>(params, PWP, BL_, Pcat,   R_, BL_ * R_ / 4);
    // dt = softplus(dt_unproj @ W_dt^T + b_dt) -> dtT[b,e,l]
    mfma_gemm<2><<<dim3(E_ / 128, BL_ / 128), 256, 0, stream>>>(Wdtcat, Pcat, b_dt, dtT, R_, 0);
    // conv + silu -> uT
    conv_silu_kernel<<<dim3(E_ / 64, L_ / 64, B_), 256, 0, stream>>>(x, cw, uT);
    // scan -> ygT
    scan_kernel<<<B_ * E_, 64, 0, stream>>>(dtT, uT, zT, params, A_log, Dp, ygT);
    // yg split (transpose) + W_out split
    split_tr<<<dim3(E_ / 64, L_ / 64, B_), 256, 0, stream>>>(ygT, Ycat);
    split_rm<<<1024, 256, 0, stream>>>(W_out, E_, E_, Wocat, E_, E_ * E_ / 4);
    // out = yg @ W_out^T
    mfma_gemm<0><<<dim3(BL_ / 128, E_ / 128), 256, 0, stream>>>(Ycat, Wocat, nullptr, out, E_, E_);
}

// Round 4
// 436.840 us; speedup vs baseline: 1.7782x; 1.1527x over previous
//
#include <hip/hip_runtime.h>
#include <math.h>

#define B_ 2
#define L_ 2048
#define E_ 1024
#define N_ 16
#define R_ 64
#define PWP 128        // padded params pitch (96 -> 128)
#define BL_ (B_*L_)    // 4096

using bf16x8 = __attribute__((ext_vector_type(8))) short;
using f32x4  = __attribute__((ext_vector_type(4))) float;

__device__ __forceinline__ float softplusf(float x) {
    return fmaxf(x, 0.0f) + log1pf(expf(-fabsf(x)));
}
__device__ __forceinline__ float siluf(float x) {
    return x / (1.0f + expf(-x));
}
__device__ __forceinline__ ushort f2bf(float f) {
    unsigned u = __float_as_uint(f);
    return (ushort)((u + 0x7fffu + ((u >> 16) & 1u)) >> 16);
}
__device__ __forceinline__ float bf2f(ushort h) {
    return __uint_as_float(((unsigned)h) << 16);
}
__device__ __forceinline__ void gload16(const ushort* g, ushort* l) {
    __builtin_amdgcn_global_load_lds((const __attribute__((address_space(1))) void*)g,
                                     (__attribute__((address_space(3))) void*)l, 16, 0, 0);
}

// src fp32 [rows_src][spitch] -> dst [rows_dst][2K] bf16 as [hi(K) | lo(K)]; pad rows zero.
__global__ __launch_bounds__(256)
void split_rm(const float* __restrict__ src, int spitch, int rows_src,
              ushort* __restrict__ dst, int K, int total4) {
    const int idx = blockIdx.x * 256 + threadIdx.x;
    if (idx >= total4) return;
    const int Kq = K >> 2;
    const int r  = idx / Kq;
    const int c4 = (idx - r * Kq) << 2;
    float f[4] = {0.f, 0.f, 0.f, 0.f};
    if (r < rows_src)
        *reinterpret_cast<float4*>(f) = *reinterpret_cast<const float4*>(src + (size_t)r * spitch + c4);
    ushort h[4], lo[4];
#pragma unroll
    for (int q = 0; q < 4; ++q) {
        h[q]  = f2bf(f[q]);
        lo[q] = f2bf(f[q] - bf2f(h[q]));
    }
    ushort* d0 = dst + (size_t)r * 2 * K + c4;
    *reinterpret_cast<uint2*>(d0)     = make_uint2((uint)h[0]  | ((uint)h[1]  << 16), (uint)h[2]  | ((uint)h[3]  << 16));
    *reinterpret_cast<uint2*>(d0 + K) = make_uint2((uint)lo[0] | ((uint)lo[1] << 16), (uint)lo[2] | ((uint)lo[3] << 16));
}

// ygT[b][e][l] fp32 -> Ycat [b*L+l][2E] bf16 hi|lo
__global__ __launch_bounds__(256)
void split_tr(const float* __restrict__ ygT, ushort* __restrict__ Ycat) {
    __shared__ float Ts[64][65];
    const int e0 = blockIdx.x * 64;
    const int l0 = blockIdx.y * 64;
    const int b  = blockIdx.z;
    const int tid = threadIdx.x;
    for (int idx = tid; idx < 64 * 64; idx += 256) {
        const int rr = idx >> 6, cc = idx & 63;
        Ts[rr][cc] = ygT[((size_t)(b * E_ + e0 + rr) << 11) + l0 + cc];
    }
    __syncthreads();
    for (int idx = tid; idx < 64 * 16; idx += 256) {
        const int rl = idx >> 4, g = idx & 15;
        ushort h[4], lo[4];
#pragma unroll
        for (int q = 0; q < 4; ++q) {
            const float f = Ts[g * 4 + q][rl];
            h[q]  = f2bf(f);
            lo[q] = f2bf(f - bf2f(h[q]));
        }
        ushort* d0 = Ycat + (size_t)(b * L_ + l0 + rl) * 2 * E_ + e0 + g * 4;
        *reinterpret_cast<uint2*>(d0)      = make_uint2((uint)h[0]  | ((uint)h[1]  << 16), (uint)h[2]  | ((uint)h[3]  << 16));
        *reinterpret_cast<uint2*>(d0 + E_) = make_uint2((uint)lo[0] | ((uint)lo[1] << 16), (uint)lo[2] | ((uint)lo[3] << 16));
    }
}

// Split-bf16 MFMA GEMM: D = A * B^T over hi|lo buffers (pitch 2*Kd each).
// Segments: A reads (hi,hi,lo), B reads (hi,lo,hi) -> Ahi*Bhi + Ahi*Blo + Alo*Bhi.
// 4 waves in 2x2 layout; wave-tile (BM/2)x(BN/2); frags 16x16x32.
// MODE 0: C[m*Ncols + n]; MODE 1: C[((b*E+e)<<11) + l]; MODE 2: MODE1 + softplus(v+bias[e])
template<int BM, int BN, int MODE>
__global__ __launch_bounds__(256)
void mfma_gemm(const ushort* __restrict__ A, const ushort* __restrict__ Bm,
               const float* __restrict__ bias, float* __restrict__ C,
               int Kd, int Ncols) {
    constexpr int WTM = BM / 2, WTN = BN / 2;
    constexpr int MI = WTM / 16, NJ = WTN / 16;
    __shared__ ushort As[BM * 32];
    __shared__ ushort Bs[BN * 32];
    const int tid  = threadIdx.x;
    const int wave = tid >> 6, lane = tid & 63;
    const int m0 = blockIdx.x * BM, n0 = blockIdx.y * BN;
    const int wr = wave >> 1, wc = wave & 1;
    const int fr = lane & 15, fg = lane >> 4;
    const int pK = 2 * Kd;
    const int K32 = Kd >> 5;

    f32x4 acc[MI][NJ];
#pragma unroll
    for (int i = 0; i < MI; ++i)
#pragma unroll
        for (int j = 0; j < NJ; ++j) { f32x4 z = {0.f, 0.f, 0.f, 0.f}; acc[i][j] = z; }

    const int lrow = lane >> 2;              // 0..15
    const int ske  = (lane & 3) * 8;         // shorts

    for (int seg = 0; seg < 3; ++seg) {
        const int ao = (seg == 2) ? Kd : 0;  // A: hi,hi,lo
        const int bo = (seg == 1) ? Kd : 0;  // B: hi,lo,hi
        for (int tt = 0; tt < K32; ++tt) {
            const int ka = ao + tt * 32, kb = bo + tt * 32;
#pragma unroll
            for (int g = 0; g < BM / 64; ++g) {
                const int srow = (wave * (BM / 64) + g) * 16 + lrow;
                gload16(A + (size_t)(m0 + srow) * pK + ka + ske, As + srow * 32 + ske);
            }
#pragma unroll
            for (int g = 0; g < BN / 64; ++g) {
                const int srow = (wave * (BN / 64) + g) * 16 + lrow;
                gload16(Bm + (size_t)(n0 + srow) * pK + kb + ske, Bs + srow * 32 + ske);
            }
            __syncthreads();

            bf16x8 av[MI], bv[NJ];
#pragma unroll
            for (int i = 0; i < MI; ++i)
                av[i] = *reinterpret_cast<const bf16x8*>(&As[(wr * WTM + i * 16 + fr) * 32 + fg * 8]);
#pragma unroll
            for (int j = 0; j < NJ; ++j)
                bv[j] = *reinterpret_cast<const bf16x8*>(&Bs[(wc * WTN + j * 16 + fr) * 32 + fg * 8]);
#pragma unroll
            for (int i = 0; i < MI; ++i)
#pragma unroll
                for (int j = 0; j < NJ; ++j)
                    acc[i][j] = __builtin_amdgcn_mfma_f32_16x16x32_bf16(av[i], bv[j], acc[i][j], 0, 0, 0);
            __syncthreads();
        }
    }

    if constexpr (MODE == 0) {
#pragma unroll
        for (int i = 0; i < MI; ++i) {
            const int m = m0 + wr * WTM + i * 16 + fg * 4;
#pragma unroll
            for (int j = 0; j < NJ; ++j) {
                const int n = n0 + wc * WTN + j * 16 + fr;
#pragma unroll
                for (int r = 0; r < 4; ++r)
                    C[(size_t)(m + r) * Ncols + n] = acc[i][j][r];
            }
        }
    } else {
        const int b  = n0 >> 11;
        const int lb = n0 - (b << 11);
#pragma unroll
        for (int i = 0; i < MI; ++i) {
            const int e = m0 + wr * WTM + i * 16 + fg * 4;
#pragma unroll
            for (int r = 0; r < 4; ++r) {
                const float bia = (MODE == 2) ? bias[e + r] : 0.0f;
                float* row = C + ((size_t)(b * E_ + e + r) << 11) + lb;
#pragma unroll
                for (int j = 0; j < NJ; ++j) {
                    float v = acc[i][j][r];
                    if constexpr (MODE == 2) v = softplusf(v + bia);
                    row[wc * WTN + j * 16 + fr] = v;
                }
            }
        }
    }
}

// depthwise causal conv (K=4) + silu; x [b,l,e] -> uT[b,e,l]
__global__ __launch_bounds__(256)
void conv_silu_kernel(const float* __restrict__ x, const float* __restrict__ cw,
                      float* __restrict__ uT) {
    __shared__ float Xt[67][65];
    const int e0 = blockIdx.x * 64;
    const int l0 = blockIdx.y * 64;
    const int b  = blockIdx.z;
    const int tid = threadIdx.x;
    for (int idx = tid; idx < 67 * 64; idx += 256) {
        const int row = idx >> 6, col = idx & 63;
        const int gl = l0 - 3 + row;
        Xt[row][col] = (gl >= 0) ? x[((size_t)b * L_ + gl) * E_ + e0 + col] : 0.0f;
    }
    __syncthreads();
    const int lL = tid & 63;
    const int w  = tid >> 6;
    for (int ee = w; ee < 64; ee += 4) {
        const int e = e0 + ee;
        const float w0 = cw[e*4+0], w1 = cw[e*4+1], w2 = cw[e*4+2], w3 = cw[e*4+3];
        const float v = w0*Xt[lL][ee] + w1*Xt[lL+1][ee] + w2*Xt[lL+2][ee] + w3*Xt[lL+3][ee];
        uT[((size_t)b * E_ + e) * L_ + l0 + lL] = siluf(v);
    }
}

// selective scan: one wave per (b,e); chunked parallel scan over L.
// H_0 = g_0; H_{l+1} = a_l H_l + g_l; output at l uses H_l.
// a_l[n] = exp2(dt_l*An2[n]); bt_l[n] = fma(a, m1, fma(d, m2, m3)) encodes the
// |A|<1e-5 select with per-channel constants (reciprocal hoisted out of the loop).
__global__ __launch_bounds__(64, 2)
void scan_kernel(const float* __restrict__ dtT, const float* __restrict__ uT,
                 const float* __restrict__ zT, const float* __restrict__ params,
                 const float* __restrict__ A_log, const float* __restrict__ Dp,
                 float* __restrict__ ygT) {
    const int c = blockIdx.x;
    const int b = c >> 10;
    const int e = c & (E_ - 1);
    const int lane = threadIdx.x;
    constexpr int CH = L_ / 64;   // 32
    constexpr float LOG2E = 1.44269504088896340736f;

    float An2[N_], m1[N_], m2[N_], m3[N_];
#pragma unroll
    for (int n = 0; n < N_; ++n) {
        const float A = -expf(A_log[e * N_ + n]);
        An2[n] = A * LOG2E;
        const bool sel = fabsf(A) < 1e-5f;
        const float rA = 1.0f / (A + 1e-10f);
        m1[n] = sel ? 0.0f : rA;
        m2[n] = sel ? 1.0f : 0.0f;
        m3[n] = sel ? 0.0f : -rA;
    }
    const float Dv = Dp[e];

    const float* dtp = dtT + ((size_t)b * E_ + e) * L_;
    const float* up  = uT  + ((size_t)b * E_ + e) * L_;
    const float* zp  = zT  + ((size_t)b * E_ + e) * L_;
    const int l0 = lane * CH;

    // ---- pass 1: per-chunk linear transform ----
    float P[N_], h[N_];
#pragma unroll
    for (int n = 0; n < N_; ++n) { P[n] = 1.0f; h[n] = 0.0f; }
#pragma unroll
    for (int j4 = 0; j4 < CH; j4 += 4) {
        float d4[4], u4[4];
        *reinterpret_cast<float4*>(d4) = *reinterpret_cast<const float4*>(dtp + l0 + j4);
        *reinterpret_cast<float4*>(u4) = *reinterpret_cast<const float4*>(up  + l0 + j4);
#pragma unroll
        for (int q = 0; q < 4; ++q) {
            const float d = d4[q], uu = u4[q];
#pragma unroll
            for (int n = 0; n < N_; ++n) {
                const float at = __builtin_amdgcn_exp2f(d * An2[n]);
                const float bt = fmaf(at, m1[n], fmaf(d, m2[n], m3[n]));
                h[n] = fmaf(at, h[n], bt * uu);
                P[n] *= at;
            }
        }
    }

    // ---- inclusive wave scan of transforms ----
#pragma unroll
    for (int off = 1; off < 64; off <<= 1) {
#pragma unroll
        for (int n = 0; n < N_; ++n) {
            const float Pp = __shfl_up(P[n], off);
            const float Lp = __shfl_up(h[n], off);
            if (lane >= off) {
                h[n] = fmaf(P[n], Lp, h[n]);
                P[n] *= Pp;
            }
        }
    }

    float cP[N_], cL[N_];
#pragma unroll
    for (int n = 0; n < N_; ++n) {
        cP[n] = __shfl_up(P[n], 1);
        cL[n] = __shfl_up(h[n], 1);
    }

    // seed: H_0 = g_0
    const float d0 = dtp[0];
    const float u0 = up[0];
#pragma unroll
    for (int n = 0; n < N_; ++n) {
        const float at0 = __builtin_amdgcn_exp2f(d0 * An2[n]);
        const float bt0 = fmaf(at0, m1[n], fmaf(d0, m2[n], m3[n]));
        const float g0 = bt0 * u0;
        h[n] = (lane == 0) ? g0 : fmaf(cP[n], g0, cL[n]);
    }

    // ---- pass 2: emit outputs in 16-step blocks (64B line-complete stores) ----
    const float* crow = params + (size_t)b * L_ * PWP + 80;   // C_proj cols [80,96)
    float* yp = ygT + ((size_t)b * E_ + e) * L_;
#pragma unroll
    for (int jb = 0; jb < CH; jb += 16) {
        float ov16[16];
#pragma unroll
        for (int j4 = 0; j4 < 16; j4 += 4) {
            const int l = l0 + jb + j4;
            float d4[4], u4[4], z4[4];
            *reinterpret_cast<float4*>(d4) = *reinterpret_cast<const float4*>(dtp + l);
            *reinterpret_cast<float4*>(u4) = *reinterpret_cast<const float4*>(up  + l);
            *reinterpret_cast<float4*>(z4) = *reinterpret_cast<const float4*>(zp  + l);
#pragma unroll
            for (int q = 0; q < 4; ++q) {
                const float d = d4[q], uu = u4[q];
                float Cv[N_];
                const float4* Cp4 = reinterpret_cast<const float4*>(crow + (size_t)(l + q) * PWP);
#pragma unroll
                for (int t = 0; t < N_ / 4; ++t)
                    *reinterpret_cast<float4*>(Cv + t * 4) = Cp4[t];
                float y = 0.0f;
#pragma unroll
                for (int n = 0; n < N_; ++n) y = fmaf(Cv[n], h[n], y);
                ov16[j4 + q] = (y + uu * Dv) * siluf(z4[q]);
#pragma unroll
                for (int n = 0; n < N_; ++n) {
                    const float at = __builtin_amdgcn_exp2f(d * An2[n]);
                    const float bt = fmaf(at, m1[n], fmaf(d, m2[n], m3[n]));
                    h[n] = fmaf(at, h[n], bt * uu);
                }
            }
        }
        float4* dst = reinterpret_cast<float4*>(yp + l0 + jb);
#pragma unroll
        for (int q = 0; q < 4; ++q)
            dst[q] = reinterpret_cast<float4*>(ov16)[q];
    }
}

extern "C" void kernel_launch(void* const* d_in, const int* in_sizes, int n_in,
                              void* d_out, int out_size, void* d_ws, size_t ws_size,
                              hipStream_t stream) {
    const float* x     = (const float*)d_in[0];
    const float* W_z   = (const float*)d_in[1];
    const float* W_p   = (const float*)d_in[2];
    const float* cw    = (const float*)d_in[3];
    const float* W_dt  = (const float*)d_in[4];
    const float* b_dt  = (const float*)d_in[5];
    const float* A_log = (const float*)d_in[6];
    const float* Dp    = (const float*)d_in[7];
    const float* W_out = (const float*)d_in[8];
    float* out = (float*)d_out;

    char* w = (char*)d_ws;
    ushort* Xcat   = (ushort*)(w);               // [4096][2048]  16.78 MB
    ushort* Wzcat  = (ushort*)(w + 16777216);    // [1024][2048]   4.19 MB
    ushort* Wpcat  = (ushort*)(w + 20971520);    // [128][2048]    0.52 MB
    ushort* Wdtcat = (ushort*)(w + 21495808);    // [1024][128]    0.26 MB
    ushort* Pcat   = (ushort*)(w + 21757952);    // [4096][128]    1.05 MB
    float*  params = (float*)(w + 22806528);     // [4096][128]    2.10 MB
    float*  zT     = (float*)(w + 24903680);     // 16.78 MB
    float*  dtT    = (float*)(w + 41680896);     // 16.78 MB
    float*  uT     = (float*)(w + 58458112);     // 16.78 MB
    float*  ygT    = (float*)(w + 75235328);     // 16.78 MB
    ushort* Ycat   = Xcat;                       // alias (Xcat dead by then)
    ushort* Wocat  = Wzcat;                      // alias (Wzcat dead by then)

    // splits
    split_rm<<<4096, 256, 0, stream>>>(x,    E_,  BL_, Xcat,  E_, BL_ * E_ / 4);
    split_rm<<<1024, 256, 0, stream>>>(W_z,  E_,  E_,  Wzcat, E_, E_ * E_ / 4);
    split_rm<<<128,  256, 0, stream>>>(W_p,  E_,  96,  Wpcat, E_, 128 * E_ / 4);
    // z = x @ W_z^T -> zT[b,e,l]   (A = W_z rows e, B = x rows bl)
    mfma_gemm<128,64,1><<<dim3(E_ / 128, BL_ / 64), 256, 0, stream>>>(Wzcat, Xcat, nullptr, zT, E_, 0);
    // params = x @ W_p^T -> [bl][128]
    mfma_gemm<64,64,0><<<dim3(BL_ / 64, 2), 256, 0, stream>>>(Xcat, Wpcat, nullptr, params, E_, PWP);
    split_rm<<<64,  256, 0, stream>>>(W_dt,   R_,  E_,  Wdtcat, R_, E_ * R_ / 4);
    split_rm<<<256, 256, 0, stream>>>(params, PWP, BL_, Pcat,   R_, BL_ * R_ / 4);
    // dt = softplus(dt_unproj @ W_dt^T + b_dt) -> dtT[b,e,l]
    mfma_gemm<128,64,2><<<dim3(E_ / 128, BL_ / 64), 256, 0, stream>>>(Wdtcat, Pcat, b_dt, dtT, R_, 0);
    // conv + silu -> uT
    conv_silu_kernel<<<dim3(E_ / 64, L_ / 64, B_), 256, 0, stream>>>(x, cw, uT);
    // scan -> ygT
    scan_kernel<<<B_ * E_, 64, 0, stream>>>(dtT, uT, zT, params, A_log, Dp, ygT);
    // yg split (transpose) + W_out split
    split_tr<<<dim3(E_ / 64, L_ / 64, B_), 256, 0, stream>>>(ygT, Ycat);
    split_rm<<<1024, 256, 0, stream>>>(W_out, E_, E_, Wocat, E_, E_ * E_ / 4);
    // out = yg @ W_out^T
    mfma_gemm<128,64,0><<<dim3(BL_ / 128, E_ / 64), 256, 0, stream>>>(Ycat, Wocat, nullptr, out, E_, E_);
}

// Round 5
// 344.452 us; speedup vs baseline: 2.2551x; 1.2682x over previous
//
#include <hip/hip_runtime.h>
#include <math.h>

#define B_ 2
#define L_ 2048
#define E_ 1024
#define N_ 16
#define R_ 64
#define PWP 128        // padded params pitch (96 -> 128)
#define BL_ (B_*L_)    // 4096

using bf16x8 = __attribute__((ext_vector_type(8))) short;
using f32x4  = __attribute__((ext_vector_type(4))) float;

__device__ __forceinline__ float softplusf(float x) {
    return fmaxf(x, 0.0f) + log1pf(expf(-fabsf(x)));
}
__device__ __forceinline__ float siluf(float x) {
    return x / (1.0f + expf(-x));
}
__device__ __forceinline__ ushort f2bf(float f) {
    unsigned u = __float_as_uint(f);
    return (ushort)((u + 0x7fffu + ((u >> 16) & 1u)) >> 16);
}
__device__ __forceinline__ float bf2f(ushort h) {
    return __uint_as_float(((unsigned)h) << 16);
}
__device__ __forceinline__ void gload16(const ushort* g, ushort* l) {
    __builtin_amdgcn_global_load_lds((const __attribute__((address_space(1))) void*)g,
                                     (__attribute__((address_space(3))) void*)l, 16, 0, 0);
}

// src fp32 [rows_src][spitch] -> dst [rows_dst][2K] bf16 as [hi(K) | lo(K)]; pad rows zero.
__global__ __launch_bounds__(256)
void split_rm(const float* __restrict__ src, int spitch, int rows_src,
              ushort* __restrict__ dst, int K, int total4) {
    const int idx = blockIdx.x * 256 + threadIdx.x;
    if (idx >= total4) return;
    const int Kq = K >> 2;
    const int r  = idx / Kq;
    const int c4 = (idx - r * Kq) << 2;
    float f[4] = {0.f, 0.f, 0.f, 0.f};
    if (r < rows_src)
        *reinterpret_cast<float4*>(f) = *reinterpret_cast<const float4*>(src + (size_t)r * spitch + c4);
    ushort h[4], lo[4];
#pragma unroll
    for (int q = 0; q < 4; ++q) {
        h[q]  = f2bf(f[q]);
        lo[q] = f2bf(f[q] - bf2f(h[q]));
    }
    ushort* d0 = dst + (size_t)r * 2 * K + c4;
    *reinterpret_cast<uint2*>(d0)     = make_uint2((uint)h[0]  | ((uint)h[1]  << 16), (uint)h[2]  | ((uint)h[3]  << 16));
    *reinterpret_cast<uint2*>(d0 + K) = make_uint2((uint)lo[0] | ((uint)lo[1] << 16), (uint)lo[2] | ((uint)lo[3] << 16));
}

// ygT[b][e][l] fp32 -> Ycat [b*L+l][2E] bf16 hi|lo
__global__ __launch_bounds__(256)
void split_tr(const float* __restrict__ ygT, ushort* __restrict__ Ycat) {
    __shared__ float Ts[64][65];
    const int e0 = blockIdx.x * 64;
    const int l0 = blockIdx.y * 64;
    const int b  = blockIdx.z;
    const int tid = threadIdx.x;
    for (int idx = tid; idx < 64 * 64; idx += 256) {
        const int rr = idx >> 6, cc = idx & 63;
        Ts[rr][cc] = ygT[((size_t)(b * E_ + e0 + rr) << 11) + l0 + cc];
    }
    __syncthreads();
    for (int idx = tid; idx < 64 * 16; idx += 256) {
        const int rl = idx >> 4, g = idx & 15;
        ushort h[4], lo[4];
#pragma unroll
        for (int q = 0; q < 4; ++q) {
            const float f = Ts[g * 4 + q][rl];
            h[q]  = f2bf(f);
            lo[q] = f2bf(f - bf2f(h[q]));
        }
        ushort* d0 = Ycat + (size_t)(b * L_ + l0 + rl) * 2 * E_ + e0 + g * 4;
        *reinterpret_cast<uint2*>(d0)      = make_uint2((uint)h[0]  | ((uint)h[1]  << 16), (uint)h[2]  | ((uint)h[3]  << 16));
        *reinterpret_cast<uint2*>(d0 + E_) = make_uint2((uint)lo[0] | ((uint)lo[1] << 16), (uint)lo[2] | ((uint)lo[3] << 16));
    }
}

// Split-bf16 MFMA GEMM: D = A * B^T over hi|lo buffers (pitch 2*Kd each).
// Segments: A reads (hi,hi,lo), B reads (hi,lo,hi) -> Ahi*Bhi + Ahi*Blo + Alo*Bhi.
// 4 waves in 2x2 layout; wave-tile (BM/2)x(BN/2); frags 16x16x32.
// MODE 0: C[m*Ncols + n]; MODE 1: C[((b*E+e)<<11) + l]; MODE 2: MODE1 + softplus(v+bias[e])
template<int BM, int BN, int MODE>
__global__ __launch_bounds__(256)
void mfma_gemm(const ushort* __restrict__ A, const ushort* __restrict__ Bm,
               const float* __restrict__ bias, float* __restrict__ C,
               int Kd, int Ncols) {
    constexpr int WTM = BM / 2, WTN = BN / 2;
    constexpr int MI = WTM / 16, NJ = WTN / 16;
    __shared__ ushort As[BM * 32];
    __shared__ ushort Bs[BN * 32];
    const int tid  = threadIdx.x;
    const int wave = tid >> 6, lane = tid & 63;
    const int m0 = blockIdx.x * BM, n0 = blockIdx.y * BN;
    const int wr = wave >> 1, wc = wave & 1;
    const int fr = lane & 15, fg = lane >> 4;
    const int pK = 2 * Kd;
    const int K32 = Kd >> 5;

    f32x4 acc[MI][NJ];
#pragma unroll
    for (int i = 0; i < MI; ++i)
#pragma unroll
        for (int j = 0; j < NJ; ++j) { f32x4 z = {0.f, 0.f, 0.f, 0.f}; acc[i][j] = z; }

    const int lrow = lane >> 2;              // 0..15
    const int ske  = (lane & 3) * 8;         // shorts

    for (int seg = 0; seg < 3; ++seg) {
        const int ao = (seg == 2) ? Kd : 0;  // A: hi,hi,lo
        const int bo = (seg == 1) ? Kd : 0;  // B: hi,lo,hi
        for (int tt = 0; tt < K32; ++tt) {
            const int ka = ao + tt * 32, kb = bo + tt * 32;
#pragma unroll
            for (int g = 0; g < BM / 64; ++g) {
                const int srow = (wave * (BM / 64) + g) * 16 + lrow;
                gload16(A + (size_t)(m0 + srow) * pK + ka + ske, As + srow * 32 + ske);
            }
#pragma unroll
            for (int g = 0; g < BN / 64; ++g) {
                const int srow = (wave * (BN / 64) + g) * 16 + lrow;
                gload16(Bm + (size_t)(n0 + srow) * pK + kb + ske, Bs + srow * 32 + ske);
            }
            __syncthreads();

            bf16x8 av[MI], bv[NJ];
#pragma unroll
            for (int i = 0; i < MI; ++i)
                av[i] = *reinterpret_cast<const bf16x8*>(&As[(wr * WTM + i * 16 + fr) * 32 + fg * 8]);
#pragma unroll
            for (int j = 0; j < NJ; ++j)
                bv[j] = *reinterpret_cast<const bf16x8*>(&Bs[(wc * WTN + j * 16 + fr) * 32 + fg * 8]);
#pragma unroll
            for (int i = 0; i < MI; ++i)
#pragma unroll
                for (int j = 0; j < NJ; ++j)
                    acc[i][j] = __builtin_amdgcn_mfma_f32_16x16x32_bf16(av[i], bv[j], acc[i][j], 0, 0, 0);
            __syncthreads();
        }
    }

    if constexpr (MODE == 0) {
#pragma unroll
        for (int i = 0; i < MI; ++i) {
            const int m = m0 + wr * WTM + i * 16 + fg * 4;
#pragma unroll
            for (int j = 0; j < NJ; ++j) {
                const int n = n0 + wc * WTN + j * 16 + fr;
#pragma unroll
                for (int r = 0; r < 4; ++r)
                    C[(size_t)(m + r) * Ncols + n] = acc[i][j][r];
            }
        }
    } else {
        const int b  = n0 >> 11;
        const int lb = n0 - (b << 11);
#pragma unroll
        for (int i = 0; i < MI; ++i) {
            const int e = m0 + wr * WTM + i * 16 + fg * 4;
#pragma unroll
            for (int r = 0; r < 4; ++r) {
                const float bia = (MODE == 2) ? bias[e + r] : 0.0f;
                float* row = C + ((size_t)(b * E_ + e + r) << 11) + lb;
#pragma unroll
                for (int j = 0; j < NJ; ++j) {
                    float v = acc[i][j][r];
                    if constexpr (MODE == 2) v = softplusf(v + bia);
                    row[wc * WTN + j * 16 + fr] = v;
                }
            }
        }
    }
}

// depthwise causal conv (K=4) + silu; x [b,l,e] -> uT[b,e,l]
__global__ __launch_bounds__(256)
void conv_silu_kernel(const float* __restrict__ x, const float* __restrict__ cw,
                      float* __restrict__ uT) {
    __shared__ float Xt[67][65];
    const int e0 = blockIdx.x * 64;
    const int l0 = blockIdx.y * 64;
    const int b  = blockIdx.z;
    const int tid = threadIdx.x;
    for (int idx = tid; idx < 67 * 64; idx += 256) {
        const int row = idx >> 6, col = idx & 63;
        const int gl = l0 - 3 + row;
        Xt[row][col] = (gl >= 0) ? x[((size_t)b * L_ + gl) * E_ + e0 + col] : 0.0f;
    }
    __syncthreads();
    const int lL = tid & 63;
    const int w  = tid >> 6;
    for (int ee = w; ee < 64; ee += 4) {
        const int e = e0 + ee;
        const float w0 = cw[e*4+0], w1 = cw[e*4+1], w2 = cw[e*4+2], w3 = cw[e*4+3];
        const float v = w0*Xt[lL][ee] + w1*Xt[lL+1][ee] + w2*Xt[lL+2][ee] + w3*Xt[lL+3][ee];
        uT[((size_t)b * E_ + e) * L_ + l0 + lL] = siluf(v);
    }
}

// selective scan: one wave per (b,e); chunked parallel scan over L.
// H_0 = g_0; H_{l+1} = a_l H_l + g_l; output at l uses H_l.
// a = exp2(dt*An2[n]); bt = fma(a, m1, fma(d, m2, m3)) encodes the |A|<1e-5 select.
// dt/u/z rows are LDS-staged once (coalesced global loads); pass-2 outputs
// overwrite the z slots in place; final store is wave-contiguous.
// LDS layout: slot(l) = (l>>5)*33 + (l&31)  (pad-33 -> conflict-free per-lane chunks)
__global__ __launch_bounds__(64)
void scan_kernel(const float* __restrict__ dtT, const float* __restrict__ uT,
                 const float* __restrict__ zT, const float* __restrict__ params,
                 const float* __restrict__ A_log, const float* __restrict__ Dp,
                 float* __restrict__ ygT) {
    __shared__ float sdt[64 * 33];
    __shared__ float su [64 * 33];
    __shared__ float sz [64 * 33];
    const int c = blockIdx.x;
    const int b = c >> 10;
    const int e = c & (E_ - 1);
    const int lane = threadIdx.x;
    constexpr int CH = L_ / 64;   // 32
    constexpr float LOG2E = 1.44269504088896340736f;

    const float* dtp = dtT + ((size_t)b * E_ + e) * L_;
    const float* up  = uT  + ((size_t)b * E_ + e) * L_;
    const float* zp  = zT  + ((size_t)b * E_ + e) * L_;

    // ---- stage dt/u/z rows into LDS (coalesced 1KB/instr) ----
#pragma unroll
    for (int it = 0; it < 8; ++it) {
        const int l = (it * 64 + lane) * 4;
        const int slot = ((l >> 5) * 33) + (l & 31);
        float4 vd = *reinterpret_cast<const float4*>(dtp + l);
        float4 vu = *reinterpret_cast<const float4*>(up  + l);
        float4 vz = *reinterpret_cast<const float4*>(zp  + l);
        sdt[slot] = vd.x; sdt[slot+1] = vd.y; sdt[slot+2] = vd.z; sdt[slot+3] = vd.w;
        su [slot] = vu.x; su [slot+1] = vu.y; su [slot+2] = vu.z; su [slot+3] = vu.w;
        sz [slot] = vz.x; sz [slot+1] = vz.y; sz [slot+2] = vz.z; sz [slot+3] = vz.w;
    }

    float An2[N_], m1[N_], m2[N_], m3[N_];
#pragma unroll
    for (int n = 0; n < N_; ++n) {
        const float A = -expf(A_log[e * N_ + n]);
        An2[n] = A * LOG2E;
        const bool sel = fabsf(A) < 1e-5f;
        const float rA = 1.0f / (A + 1e-10f);
        m1[n] = sel ? 0.0f : rA;
        m2[n] = sel ? 1.0f : 0.0f;
        m3[n] = sel ? 0.0f : -rA;
    }
    const float Dv = Dp[e];
    __syncthreads();

    const int base = lane * 33;

    // ---- pass 1: per-chunk linear transform ----
    float P[N_], h[N_];
#pragma unroll
    for (int n = 0; n < N_; ++n) { P[n] = 1.0f; h[n] = 0.0f; }
#pragma unroll 4
    for (int j = 0; j < CH; ++j) {
        const float d  = sdt[base + j];
        const float uu = su [base + j];
#pragma unroll
        for (int n = 0; n < N_; ++n) {
            const float at = __builtin_amdgcn_exp2f(d * An2[n]);
            const float bt = fmaf(at, m1[n], fmaf(d, m2[n], m3[n]));
            h[n] = fmaf(at, h[n], bt * uu);
            P[n] *= at;
        }
    }

    // ---- inclusive wave scan of transforms ----
#pragma unroll
    for (int off = 1; off < 64; off <<= 1) {
#pragma unroll
        for (int n = 0; n < N_; ++n) {
            const float Pp = __shfl_up(P[n], off);
            const float Lp = __shfl_up(h[n], off);
            if (lane >= off) {
                h[n] = fmaf(P[n], Lp, h[n]);
                P[n] *= Pp;
            }
        }
    }

    float cP[N_], cL[N_];
#pragma unroll
    for (int n = 0; n < N_; ++n) {
        cP[n] = __shfl_up(P[n], 1);
        cL[n] = __shfl_up(h[n], 1);
    }

    // seed: H_0 = g_0 (slot 0 broadcast)
    const float d0 = sdt[0];
    const float u0 = su[0];
#pragma unroll
    for (int n = 0; n < N_; ++n) {
        const float at0 = __builtin_amdgcn_exp2f(d0 * An2[n]);
        const float bt0 = fmaf(at0, m1[n], fmaf(d0, m2[n], m3[n]));
        const float g0 = bt0 * u0;
        h[n] = (lane == 0) ? g0 : fmaf(cP[n], g0, cL[n]);
    }

    // ---- pass 2: outputs overwrite z slots in place ----
    const float* crow = params + (size_t)b * L_ * PWP + 80;   // C_proj cols [80,96)
    const int l0 = lane * CH;
#pragma unroll 4
    for (int j = 0; j < CH; ++j) {
        const float d  = sdt[base + j];
        const float uu = su [base + j];
        const float zv = sz [base + j];
        float Cv[N_];
        const float4* Cp4 = reinterpret_cast<const float4*>(crow + (size_t)(l0 + j) * PWP);
#pragma unroll
        for (int t = 0; t < N_ / 4; ++t)
            *reinterpret_cast<float4*>(Cv + t * 4) = Cp4[t];
        float y = 0.0f;
#pragma unroll
        for (int n = 0; n < N_; ++n) y = fmaf(Cv[n], h[n], y);
        sz[base + j] = (y + uu * Dv) * siluf(zv);
        if (j < CH - 1) {   // final update is dead
#pragma unroll
            for (int n = 0; n < N_; ++n) {
                const float at = __builtin_amdgcn_exp2f(d * An2[n]);
                const float bt = fmaf(at, m1[n], fmaf(d, m2[n], m3[n]));
                h[n] = fmaf(at, h[n], bt * uu);
            }
        }
    }
    __syncthreads();

    // ---- coalesced store of outputs ----
    float* yp = ygT + ((size_t)b * E_ + e) * L_;
#pragma unroll
    for (int it = 0; it < 8; ++it) {
        const int l = (it * 64 + lane) * 4;
        const int slot = ((l >> 5) * 33) + (l & 31);
        float4 o;
        o.x = sz[slot]; o.y = sz[slot+1]; o.z = sz[slot+2]; o.w = sz[slot+3];
        *reinterpret_cast<float4*>(yp + l) = o;
    }
}

extern "C" void kernel_launch(void* const* d_in, const int* in_sizes, int n_in,
                              void* d_out, int out_size, void* d_ws, size_t ws_size,
                              hipStream_t stream) {
    const float* x     = (const float*)d_in[0];
    const float* W_z   = (const float*)d_in[1];
    const float* W_p   = (const float*)d_in[2];
    const float* cw    = (const float*)d_in[3];
    const float* W_dt  = (const float*)d_in[4];
    const float* b_dt  = (const float*)d_in[5];
    const float* A_log = (const float*)d_in[6];
    const float* Dp    = (const float*)d_in[7];
    const float* W_out = (const float*)d_in[8];
    float* out = (float*)d_out;

    char* w = (char*)d_ws;
    ushort* Xcat   = (ushort*)(w);               // [4096][2048]  16.78 MB
    ushort* Wzcat  = (ushort*)(w + 16777216);    // [1024][2048]   4.19 MB
    ushort* Wpcat  = (ushort*)(w + 20971520);    // [128][2048]    0.52 MB
    ushort* Wdtcat = (ushort*)(w + 21495808);    // [1024][128]    0.26 MB
    ushort* Pcat   = (ushort*)(w + 21757952);    // [4096][128]    1.05 MB
    float*  params = (float*)(w + 22806528);     // [4096][128]    2.10 MB
    float*  zT     = (float*)(w + 24903680);     // 16.78 MB
    float*  dtT    = (float*)(w + 41680896);     // 16.78 MB
    float*  uT     = (float*)(w + 58458112);     // 16.78 MB
    float*  ygT    = (float*)(w + 75235328);     // 16.78 MB
    ushort* Ycat   = Xcat;                       // alias (Xcat dead by then)
    ushort* Wocat  = Wzcat;                      // alias (Wzcat dead by then)

    // splits
    split_rm<<<4096, 256, 0, stream>>>(x,    E_,  BL_, Xcat,  E_, BL_ * E_ / 4);
    split_rm<<<1024, 256, 0, stream>>>(W_z,  E_,  E_,  Wzcat, E_, E_ * E_ / 4);
    split_rm<<<128,  256, 0, stream>>>(W_p,  E_,  96,  Wpcat, E_, 128 * E_ / 4);
    // z = x @ W_z^T -> zT[b,e,l]   (A = W_z rows e, B = x rows bl)
    mfma_gemm<128,64,1><<<dim3(E_ / 128, BL_ / 64), 256, 0, stream>>>(Wzcat, Xcat, nullptr, zT, E_, 0);
    // params = x @ W_p^T -> [bl][128]
    mfma_gemm<64,64,0><<<dim3(BL_ / 64, 2), 256, 0, stream>>>(Xcat, Wpcat, nullptr, params, E_, PWP);
    split_rm<<<64,  256, 0, stream>>>(W_dt,   R_,  E_,  Wdtcat, R_, E_ * R_ / 4);
    split_rm<<<256, 256, 0, stream>>>(params, PWP, BL_, Pcat,   R_, BL_ * R_ / 4);
    // dt = softplus(dt_unproj @ W_dt^T + b_dt) -> dtT[b,e,l]
    mfma_gemm<128,64,2><<<dim3(E_ / 128, BL_ / 64), 256, 0, stream>>>(Wdtcat, Pcat, b_dt, dtT, R_, 0);
    // conv + silu -> uT
    conv_silu_kernel<<<dim3(E_ / 64, L_ / 64, B_), 256, 0, stream>>>(x, cw, uT);
    // scan -> ygT
    scan_kernel<<<B_ * E_, 64, 0, stream>>>(dtT, uT, zT, params, A_log, Dp, ygT);
    // yg split (transpose) + W_out split
    split_tr<<<dim3(E_ / 64, L_ / 64, B_), 256, 0, stream>>>(ygT, Ycat);
    split_rm<<<1024, 256, 0, stream>>>(W_out, E_, E_, Wocat, E_, E_ * E_ / 4);
    // out = yg @ W_out^T
    mfma_gemm<128,64,0><<<dim3(BL_ / 128, E_ / 64), 256, 0, stream>>>(Ycat, Wocat, nullptr, out, E_, E_);
}

// Round 7
// 300.683 us; speedup vs baseline: 2.5833x; 1.1456x over previous
//
#include <hip/hip_runtime.h>
#include <math.h>

#define B_ 2
#define L_ 2048
#define E_ 1024
#define N_ 16
#define R_ 64
#define PWP 128        // padded params pitch (96 -> 128)
#define BL_ (B_*L_)    // 4096

using bf16x8 = __attribute__((ext_vector_type(8))) short;
using f32x4  = __attribute__((ext_vector_type(4))) float;

__device__ __forceinline__ float softplusf(float x) {
    return fmaxf(x, 0.0f) + log1pf(expf(-fabsf(x)));
}
__device__ __forceinline__ float siluf(float x) {
    return x / (1.0f + expf(-x));
}
__device__ __forceinline__ ushort f2bf(float f) {
    unsigned u = __float_as_uint(f);
    return (ushort)((u + 0x7fffu + ((u >> 16) & 1u)) >> 16);
}
__device__ __forceinline__ float bf2f(ushort h) {
    return __uint_as_float(((unsigned)h) << 16);
}
__device__ __forceinline__ void gload16(const ushort* g, ushort* l) {
    __builtin_amdgcn_global_load_lds((const __attribute__((address_space(1))) void*)g,
                                     (__attribute__((address_space(3))) void*)l, 16, 0, 0);
}

// fp32 [rows_src][spitch] -> [rows_dst][2K] bf16 as [hi(K)|lo(K)]; pad rows zero.
__device__ __forceinline__ void split_body(const float* __restrict__ src, int spitch,
                                           int rows_src, ushort* __restrict__ dst,
                                           int K, int total4, int idx) {
    if (idx >= total4) return;
    const int Kq = K >> 2;
    const int r  = idx / Kq;
    const int c4 = (idx - r * Kq) << 2;
    float f[4] = {0.f, 0.f, 0.f, 0.f};
    if (r < rows_src)
        *reinterpret_cast<float4*>(f) = *reinterpret_cast<const float4*>(src + (size_t)r * spitch + c4);
    ushort h[4], lo[4];
#pragma unroll
    for (int q = 0; q < 4; ++q) {
        h[q]  = f2bf(f[q]);
        lo[q] = f2bf(f[q] - bf2f(h[q]));
    }
    ushort* d0 = dst + (size_t)r * 2 * K + c4;
    *reinterpret_cast<uint2*>(d0)     = make_uint2((uint)h[0]  | ((uint)h[1]  << 16), (uint)h[2]  | ((uint)h[3]  << 16));
    *reinterpret_cast<uint2*>(d0 + K) = make_uint2((uint)lo[0] | ((uint)lo[1] << 16), (uint)lo[2] | ((uint)lo[3] << 16));
}

__global__ __launch_bounds__(256)
void split_rm(const float* __restrict__ src, int spitch, int rows_src,
              ushort* __restrict__ dst, int K, int total4) {
    split_body(src, spitch, rows_src, dst, K, total4, blockIdx.x * 256 + threadIdx.x);
}

// merged W_z / W_p / W_dt splits (blockIdx.y selects the job)
__global__ __launch_bounds__(256)
void split_w3(const float* __restrict__ Wz, const float* __restrict__ Wp,
              const float* __restrict__ Wdt, ushort* __restrict__ WzC,
              ushort* __restrict__ WpC, ushort* __restrict__ WdtC) {
    const int idx = blockIdx.x * 256 + threadIdx.x;
    if (blockIdx.y == 0)      split_body(Wz,  E_, E_,  WzC,  E_, E_ * E_ / 4, idx);
    else if (blockIdx.y == 1) split_body(Wp,  E_, 96,  WpC,  E_, 128 * E_ / 4, idx);
    else                      split_body(Wdt, R_, E_,  WdtC, R_, E_ * R_ / 4, idx);
}

// ygT[b][e][l] fp32 -> Ycat [b*L+l][2E] bf16 hi|lo
__global__ __launch_bounds__(256)
void split_tr(const float* __restrict__ ygT, ushort* __restrict__ Ycat) {
    __shared__ float Ts[64][65];
    const int e0 = blockIdx.x * 64;
    const int l0 = blockIdx.y * 64;
    const int b  = blockIdx.z;
    const int tid = threadIdx.x;
    for (int idx = tid; idx < 64 * 64; idx += 256) {
        const int rr = idx >> 6, cc = idx & 63;
        Ts[rr][cc] = ygT[((size_t)(b * E_ + e0 + rr) << 11) + l0 + cc];
    }
    __syncthreads();
    for (int idx = tid; idx < 64 * 16; idx += 256) {
        const int rl = idx >> 4, g = idx & 15;
        ushort h[4], lo[4];
#pragma unroll
        for (int q = 0; q < 4; ++q) {
            const float f = Ts[g * 4 + q][rl];
            h[q]  = f2bf(f);
            lo[q] = f2bf(f - bf2f(h[q]));
        }
        ushort* d0 = Ycat + (size_t)(b * L_ + l0 + rl) * 2 * E_ + e0 + g * 4;
        *reinterpret_cast<uint2*>(d0)      = make_uint2((uint)h[0]  | ((uint)h[1]  << 16), (uint)h[2]  | ((uint)h[3]  << 16));
        *reinterpret_cast<uint2*>(d0 + E_) = make_uint2((uint)lo[0] | ((uint)lo[1] << 16), (uint)lo[2] | ((uint)lo[3] << 16));
    }
}

// Split-bf16 MFMA GEMM, BK=64 staging with XOR-swizzled LDS (rule-21: linear
// global_load_lds dest + inverse-swizzled global source + swizzled ds_read).
// Segments: A reads (hi,hi,lo), B reads (hi,lo,hi) -> Ahi*Bhi + Ahi*Blo + Alo*Bhi.
// 4 waves 2x2; wave-tile (BM/2)x(BN/2); frags 16x16x32; K order preserved vs BK=32.
// MODE 0: C[m*Ncols+n]; MODE 1: C[((b*E+e)<<11)+l]; MODE 2: MODE1+softplus(v+bias[e]);
// MODE 3: params epilogue — fp32 C cols [80,96) + hi|lo bf16 of cols [0,64) into P2.
template<int BM, int BN, int MODE>
__global__ __launch_bounds__(256)
void mfma_gemm(const ushort* __restrict__ A, const ushort* __restrict__ Bm,
               const float* __restrict__ bias, ushort* __restrict__ P2,
               float* __restrict__ C, int Kd, int Ncols) {
    constexpr int WTM = BM / 2, WTN = BN / 2;
    constexpr int MI = WTM / 16, NJ = WTN / 16;
    __shared__ ushort As[BM * 64];
    __shared__ ushort Bs[BN * 64];
    const int tid  = threadIdx.x;
    const int wave = tid >> 6, lane = tid & 63;
    const int m0 = blockIdx.x * BM, n0 = blockIdx.y * BN;
    const int wr = wave >> 1, wc = wave & 1;
    const int fr = lane & 15, fg = lane >> 4;
    const int kxor = (fr & 7) << 3;          // ds_read col swizzle (shorts)
    const int pK = 2 * Kd;
    const int K64 = Kd >> 6;                 // Kd=64 -> 1

    f32x4 acc[MI][NJ];
#pragma unroll
    for (int i = 0; i < MI; ++i)
#pragma unroll
        for (int j = 0; j < NJ; ++j) { f32x4 z = {0.f, 0.f, 0.f, 0.f}; acc[i][j] = z; }

    const int lrow = lane >> 3;              // 0..7
    const int lc   = lane & 7;               // 16B chunk idx

    for (int seg = 0; seg < 3; ++seg) {
        const int ao = (seg == 2) ? Kd : 0;  // A: hi,hi,lo
        const int bo = (seg == 1) ? Kd : 0;  // B: hi,lo,hi
        for (int tt = 0; tt < K64; ++tt) {
            const int ka = ao + tt * 64, kb = bo + tt * 64;
#pragma unroll
            for (int g = 0; g < BM / 32; ++g) {
                const int srow = (wave * (BM / 32) + g) * 8 + lrow;
                gload16(A + (size_t)(m0 + srow) * pK + ka + ((lc ^ (srow & 7)) * 8),
                        As + srow * 64 + lc * 8);
            }
#pragma unroll
            for (int g = 0; g < BN / 32; ++g) {
                const int srow = (wave * (BN / 32) + g) * 8 + lrow;
                gload16(Bm + (size_t)(n0 + srow) * pK + kb + ((lc ^ (srow & 7)) * 8),
                        Bs + srow * 64 + lc * 8);
            }
            __syncthreads();

            bf16x8 av[2][MI], bv[2][NJ];
#pragma unroll
            for (int ks = 0; ks < 2; ++ks) {
#pragma unroll
                for (int i = 0; i < MI; ++i) {
                    const int row = wr * WTM + i * 16 + fr;
                    av[ks][i] = *reinterpret_cast<const bf16x8*>(&As[row * 64 + ((ks * 32 + fg * 8) ^ kxor)]);
                }
#pragma unroll
                for (int j = 0; j < NJ; ++j) {
                    const int row = wc * WTN + j * 16 + fr;
                    bv[ks][j] = *reinterpret_cast<const bf16x8*>(&Bs[row * 64 + ((ks * 32 + fg * 8) ^ kxor)]);
                }
            }
#pragma unroll
            for (int ks = 0; ks < 2; ++ks)
#pragma unroll
                for (int i = 0; i < MI; ++i)
#pragma unroll
                    for (int j = 0; j < NJ; ++j)
                        acc[i][j] = __builtin_amdgcn_mfma_f32_16x16x32_bf16(av[ks][i], bv[ks][j], acc[i][j], 0, 0, 0);
            __syncthreads();
        }
    }

    if constexpr (MODE == 0) {
#pragma unroll
        for (int i = 0; i < MI; ++i) {
            const int m = m0 + wr * WTM + i * 16 + fg * 4;
#pragma unroll
            for (int j = 0; j < NJ; ++j) {
                const int n = n0 + wc * WTN + j * 16 + fr;
#pragma unroll
                for (int r = 0; r < 4; ++r)
                    C[(size_t)(m + r) * Ncols + n] = acc[i][j][r];
            }
        }
    } else if constexpr (MODE == 3) {
#pragma unroll
        for (int i = 0; i < MI; ++i) {
            const int m = m0 + wr * WTM + i * 16 + fg * 4;
#pragma unroll
            for (int j = 0; j < NJ; ++j) {
                const int n = n0 + wc * WTN + j * 16 + fr;
#pragma unroll
                for (int r = 0; r < 4; ++r) {
                    const float v = acc[i][j][r];
                    const int mm = m + r;
                    if (n < 64) {
                        const ushort hh = f2bf(v);
                        P2[(size_t)mm * 128 + n]      = hh;
                        P2[(size_t)mm * 128 + 64 + n] = f2bf(v - bf2f(hh));
                    } else if (n >= 80 && n < 96) {
                        C[(size_t)mm * Ncols + n] = v;
                    }
                }
            }
        }
    } else {
        const int b  = n0 >> 11;
        const int lb = n0 - (b << 11);
#pragma unroll
        for (int i = 0; i < MI; ++i) {
            const int e = m0 + wr * WTM + i * 16 + fg * 4;
#pragma unroll
            for (int r = 0; r < 4; ++r) {
                const float bia = (MODE == 2) ? bias[e + r] : 0.0f;
                float* row = C + ((size_t)(b * E_ + e + r) << 11) + lb;
#pragma unroll
                for (int j = 0; j < NJ; ++j) {
                    float v = acc[i][j][r];
                    if constexpr (MODE == 2) v = softplusf(v + bia);
                    row[wc * WTN + j * 16 + fr] = v;
                }
            }
        }
    }
}

// depthwise causal conv (K=4) + silu; x [b,l,e] -> uT[b,e,l]
__global__ __launch_bounds__(256)
void conv_silu_kernel(const float* __restrict__ x, const float* __restrict__ cw,
                      float* __restrict__ uT) {
    __shared__ float Xt[67][65];
    const int e0 = blockIdx.x * 64;
    const int l0 = blockIdx.y * 64;
    const int b  = blockIdx.z;
    const int tid = threadIdx.x;
    for (int idx = tid; idx < 67 * 64; idx += 256) {
        const int row = idx >> 6, col = idx & 63;
        const int gl = l0 - 3 + row;
        Xt[row][col] = (gl >= 0) ? x[((size_t)b * L_ + gl) * E_ + e0 + col] : 0.0f;
    }
    __syncthreads();
    const int lL = tid & 63;
    const int w  = tid >> 6;
    for (int ee = w; ee < 64; ee += 4) {
        const int e = e0 + ee;
        const float w0 = cw[e*4+0], w1 = cw[e*4+1], w2 = cw[e*4+2], w3 = cw[e*4+3];
        const float v = w0*Xt[lL][ee] + w1*Xt[lL+1][ee] + w2*Xt[lL+2][ee] + w3*Xt[lL+3][ee];
        uT[((size_t)b * E_ + e) * L_ + l0 + lL] = siluf(v);
    }
}

// selective scan: one wave per (b,e); chunked parallel scan over L.
// H_0 = g_0; H_{l+1} = a_l H_l + g_l; output at l uses H_l.
// dt/u LDS-staged (pad-33 chunk layout, conflict-free); z streamed from global
// in pass 2 (per-lane contiguous, L2/LLC-resident); outputs overwrite sdt slots.
__global__ __launch_bounds__(64)
void scan_kernel(const float* __restrict__ dtT, const float* __restrict__ uT,
                 const float* __restrict__ zT, const float* __restrict__ params,
                 const float* __restrict__ A_log, const float* __restrict__ Dp,
                 float* __restrict__ ygT) {
    __shared__ float sdt[64 * 33];
    __shared__ float su [64 * 33];
    const int c = blockIdx.x;
    const int b = c >> 10;
    const int e = c & (E_ - 1);
    const int lane = threadIdx.x;
    constexpr int CH = L_ / 64;   // 32
    constexpr float LOG2E = 1.44269504088896340736f;

    const float* dtp = dtT + ((size_t)b * E_ + e) * L_;
    const float* up  = uT  + ((size_t)b * E_ + e) * L_;
    const float* zp  = zT  + ((size_t)b * E_ + e) * L_;

    // ---- stage dt/u rows into LDS (coalesced 1KB/instr) ----
#pragma unroll
    for (int it = 0; it < 8; ++it) {
        const int l = (it * 64 + lane) * 4;
        const int slot = ((l >> 5) * 33) + (l & 31);
        float4 vd = *reinterpret_cast<const float4*>(dtp + l);
        float4 vu = *reinterpret_cast<const float4*>(up  + l);
        sdt[slot] = vd.x; sdt[slot+1] = vd.y; sdt[slot+2] = vd.z; sdt[slot+3] = vd.w;
        su [slot] = vu.x; su [slot+1] = vu.y; su [slot+2] = vu.z; su [slot+3] = vu.w;
    }

    float An2[N_], m1[N_], m2[N_], m3[N_];
#pragma unroll
    for (int n = 0; n < N_; ++n) {
        const float A = -expf(A_log[e * N_ + n]);
        An2[n] = A * LOG2E;
        const bool sel = fabsf(A) < 1e-5f;
        const float rA = 1.0f / (A + 1e-10f);
        m1[n] = sel ? 0.0f : rA;
        m2[n] = sel ? 1.0f : 0.0f;
        m3[n] = sel ? 0.0f : -rA;
    }
    const float Dv = Dp[e];
    __syncthreads();

    const int base = lane * 33;

    // ---- pass 1: per-chunk linear transform ----
    float P[N_], h[N_];
#pragma unroll
    for (int n = 0; n < N_; ++n) { P[n] = 1.0f; h[n] = 0.0f; }
#pragma unroll 4
    for (int j = 0; j < CH; ++j) {
        const float d  = sdt[base + j];
        const float uu = su [base + j];
#pragma unroll
        for (int n = 0; n < N_; ++n) {
            const float at = __builtin_amdgcn_exp2f(d * An2[n]);
            const float bt = fmaf(at, m1[n], fmaf(d, m2[n], m3[n]));
            h[n] = fmaf(at, h[n], bt * uu);
            P[n] *= at;
        }
    }

    // ---- inclusive wave scan of transforms ----
#pragma unroll
    for (int off = 1; off < 64; off <<= 1) {
#pragma unroll
        for (int n = 0; n < N_; ++n) {
            const float Pp = __shfl_up(P[n], off);
            const float Lp = __shfl_up(h[n], off);
            if (lane >= off) {
                h[n] = fmaf(P[n], Lp, h[n]);
                P[n] *= Pp;
            }
        }
    }

    float cP[N_], cL[N_];
#pragma unroll
    for (int n = 0; n < N_; ++n) {
        cP[n] = __shfl_up(P[n], 1);
        cL[n] = __shfl_up(h[n], 1);
    }

    // seed: H_0 = g_0 (slot 0 broadcast; read before any pass-2 overwrite)
    const float d0 = sdt[0];
    const float u0 = su[0];
#pragma unroll
    for (int n = 0; n < N_; ++n) {
        const float at0 = __builtin_amdgcn_exp2f(d0 * An2[n]);
        const float bt0 = fmaf(at0, m1[n], fmaf(d0, m2[n], m3[n]));
        const float g0 = bt0 * u0;
        h[n] = (lane == 0) ? g0 : fmaf(cP[n], g0, cL[n]);
    }

    // ---- pass 2: outputs overwrite sdt slots (dt[j] dead after its update) ----
    const float* crow = params + (size_t)b * L_ * PWP + 80;   // C_proj cols [80,96)
    const int l0 = lane * CH;
#pragma unroll 4
    for (int j = 0; j < CH; ++j) {
        const float d  = sdt[base + j];
        const float uu = su [base + j];
        const float zv = zp[l0 + j];
        float Cv[N_];
        const float4* Cp4 = reinterpret_cast<const float4*>(crow + (size_t)(l0 + j) * PWP);
#pragma unroll
        for (int t = 0; t < N_ / 4; ++t)
            *reinterpret_cast<float4*>(Cv + t * 4) = Cp4[t];
        float y = 0.0f;
#pragma unroll
        for (int n = 0; n < N_; ++n) y = fmaf(Cv[n], h[n], y);
        const float outv = (y + uu * Dv) * siluf(zv);
        if (j < CH - 1) {   // final update is dead
#pragma unroll
            for (int n = 0; n < N_; ++n) {
                const float at = __builtin_amdgcn_exp2f(d * An2[n]);
                const float bt = fmaf(at, m1[n], fmaf(d, m2[n], m3[n]));
                h[n] = fmaf(at, h[n], bt * uu);
            }
        }
        sdt[base + j] = outv;
    }
    __syncthreads();

    // ---- coalesced store of outputs ----
    float* yp = ygT + ((size_t)b * E_ + e) * L_;
#pragma unroll
    for (int it = 0; it < 8; ++it) {
        const int l = (it * 64 + lane) * 4;
        const int slot = ((l >> 5) * 33) + (l & 31);
        float4 o;
        o.x = sdt[slot]; o.y = sdt[slot+1]; o.z = sdt[slot+2]; o.w = sdt[slot+3];
        *reinterpret_cast<float4*>(yp + l) = o;
    }
}

extern "C" void kernel_launch(void* const* d_in, const int* in_sizes, int n_in,
                              void* d_out, int out_size, void* d_ws, size_t ws_size,
                              hipStream_t stream) {
    const float* x     = (const float*)d_in[0];
    const float* W_z   = (const float*)d_in[1];
    const float* W_p   = (const float*)d_in[2];
    const float* cw    = (const float*)d_in[3];
    const float* W_dt  = (const float*)d_in[4];
    const float* b_dt  = (const float*)d_in[5];
    const float* A_log = (const float*)d_in[6];
    const float* Dp    = (const float*)d_in[7];
    const float* W_out = (const float*)d_in[8];
    float* out = (float*)d_out;

    char* w = (char*)d_ws;
    ushort* Xcat   = (ushort*)(w);               // [4096][2048]  16.78 MB
    ushort* Wzcat  = (ushort*)(w + 16777216);    // [1024][2048]   4.19 MB
    ushort* Wpcat  = (ushort*)(w + 20971520);    // [128][2048]    0.52 MB
    ushort* Wdtcat = (ushort*)(w + 21495808);    // [1024][128]    0.26 MB
    ushort* Pcat   = (ushort*)(w + 21757952);    // [4096][128]    1.05 MB
    float*  params = (float*)(w + 22806528);     // [4096][128]    2.10 MB
    float*  zT     = (float*)(w + 24903680);     // 16.78 MB
    float*  dtT    = (float*)(w + 41680896);     // 16.78 MB
    float*  uT     = (float*)(w + 58458112);     // 16.78 MB
    float*  ygT    = (float*)(w + 75235328);     // 16.78 MB
    ushort* Ycat   = Xcat;                       // alias (Xcat dead by then)
    ushort* Wocat  = Wzcat;                      // alias (Wzcat dead by then)

    // x split + merged weight splits
    split_rm<<<4096, 256, 0, stream>>>(x, E_, BL_, Xcat, E_, BL_ * E_ / 4);
    split_w3<<<dim3(1024, 3), 256, 0, stream>>>(W_z, W_p, W_dt, Wzcat, Wpcat, Wdtcat);
    // z = x @ W_z^T -> zT[b,e,l]   (A = W_z rows e, B = x rows bl)
    mfma_gemm<128,64,1><<<dim3(E_ / 128, BL_ / 64), 256, 0, stream>>>(
        Wzcat, Xcat, nullptr, nullptr, zT, E_, 0);
    // params = x @ W_p^T: fp32 C_proj cols [80,96) + bf16 hi|lo dt_unproj -> Pcat
    mfma_gemm<64,64,3><<<dim3(BL_ / 64, 2), 256, 0, stream>>>(
        Xcat, Wpcat, nullptr, Pcat, params, E_, PWP);
    // dt = softplus(dt_unproj @ W_dt^T + b_dt) -> dtT[b,e,l]
    mfma_gemm<128,64,2><<<dim3(E_ / 128, BL_ / 64), 256, 0, stream>>>(
        Wdtcat, Pcat, b_dt, nullptr, dtT, R_, 0);
    // conv + silu -> uT
    conv_silu_kernel<<<dim3(E_ / 64, L_ / 64, B_), 256, 0, stream>>>(x, cw, uT);
    // scan -> ygT
    scan_kernel<<<B_ * E_, 64, 0, stream>>>(dtT, uT, zT, params, A_log, Dp, ygT);
    // yg split (transpose) + W_out split
    split_tr<<<dim3(E_ / 64, L_ / 64, B_), 256, 0, stream>>>(ygT, Ycat);
    split_rm<<<1024, 256, 0, stream>>>(W_out, E_, E_, Wocat, E_, E_ * E_ / 4);
    // out = yg @ W_out^T
    mfma_gemm<128,64,0><<<dim3(BL_ / 128, E_ / 64), 256, 0, stream>>>(
        Ycat, Wocat, nullptr, nullptr, out, E_, E_);
}

// Round 9
// 291.566 us; speedup vs baseline: 2.6641x; 1.0313x over previous
//
#include <hip/hip_runtime.h>
#include <math.h>

#define B_ 2
#define L_ 2048
#define E_ 1024
#define N_ 16
#define R_ 64
#define PWP 128        // padded params pitch (96 -> 128)
#define BL_ (B_*L_)    // 4096

using bf16x8 = __attribute__((ext_vector_type(8))) short;
using f32x4  = __attribute__((ext_vector_type(4))) float;

__device__ __forceinline__ float softplusf(float x) {
    return fmaxf(x, 0.0f) + log1pf(expf(-fabsf(x)));
}
__device__ __forceinline__ float siluf(float x) {
    return x / (1.0f + expf(-x));
}
__device__ __forceinline__ ushort f2bf(float f) {
    unsigned u = __float_as_uint(f);
    return (ushort)((u + 0x7fffu + ((u >> 16) & 1u)) >> 16);
}
__device__ __forceinline__ float bf2f(ushort h) {
    return __uint_as_float(((unsigned)h) << 16);
}
__device__ __forceinline__ void gload16(const ushort* g, ushort* l) {
    __builtin_amdgcn_global_load_lds((const __attribute__((address_space(1))) void*)g,
                                     (__attribute__((address_space(3))) void*)l, 16, 0, 0);
}

// fp32 [rows_src][spitch] -> [rows_dst][2K] bf16 as [hi(K)|lo(K)]; pad rows zero.
__device__ __forceinline__ void split_body(const float* __restrict__ src, int spitch,
                                           int rows_src, ushort* __restrict__ dst,
                                           int K, int total4, int idx) {
    if (idx >= total4) return;
    const int Kq = K >> 2;
    const int r  = idx / Kq;
    const int c4 = (idx - r * Kq) << 2;
    float f[4] = {0.f, 0.f, 0.f, 0.f};
    if (r < rows_src)
        *reinterpret_cast<float4*>(f) = *reinterpret_cast<const float4*>(src + (size_t)r * spitch + c4);
    ushort h[4], lo[4];
#pragma unroll
    for (int q = 0; q < 4; ++q) {
        h[q]  = f2bf(f[q]);
        lo[q] = f2bf(f[q] - bf2f(h[q]));
    }
    ushort* d0 = dst + (size_t)r * 2 * K + c4;
    *reinterpret_cast<uint2*>(d0)     = make_uint2((uint)h[0]  | ((uint)h[1]  << 16), (uint)h[2]  | ((uint)h[3]  << 16));
    *reinterpret_cast<uint2*>(d0 + K) = make_uint2((uint)lo[0] | ((uint)lo[1] << 16), (uint)lo[2] | ((uint)lo[3] << 16));
}

__global__ __launch_bounds__(256)
void split_rm(const float* __restrict__ src, int spitch, int rows_src,
              ushort* __restrict__ dst, int K, int total4) {
    split_body(src, spitch, rows_src, dst, K, total4, blockIdx.x * 256 + threadIdx.x);
}

// merged W_z / W_p / W_dt splits (blockIdx.y selects the job)
__global__ __launch_bounds__(256)
void split_w3(const float* __restrict__ Wz, const float* __restrict__ Wp,
              const float* __restrict__ Wdt, ushort* __restrict__ WzC,
              ushort* __restrict__ WpC, ushort* __restrict__ WdtC) {
    const int idx = blockIdx.x * 256 + threadIdx.x;
    if (blockIdx.y == 0)      split_body(Wz,  E_, E_,  WzC,  E_, E_ * E_ / 4, idx);
    else if (blockIdx.y == 1) split_body(Wp,  E_, 96,  WpC,  E_, 128 * E_ / 4, idx);
    else                      split_body(Wdt, R_, E_,  WdtC, R_, E_ * R_ / 4, idx);
}

// ygT[b][e][l] fp32 -> Ycat [b*L+l][2E] bf16 hi|lo
__global__ __launch_bounds__(256)
void split_tr(const float* __restrict__ ygT, ushort* __restrict__ Ycat) {
    __shared__ float Ts[64][65];
    const int e0 = blockIdx.x * 64;
    const int l0 = blockIdx.y * 64;
    const int b  = blockIdx.z;
    const int tid = threadIdx.x;
    for (int idx = tid; idx < 64 * 64; idx += 256) {
        const int rr = idx >> 6, cc = idx & 63;
        Ts[rr][cc] = ygT[((size_t)(b * E_ + e0 + rr) << 11) + l0 + cc];
    }
    __syncthreads();
    for (int idx = tid; idx < 64 * 16; idx += 256) {
        const int rl = idx >> 4, g = idx & 15;
        ushort h[4], lo[4];
#pragma unroll
        for (int q = 0; q < 4; ++q) {
            const float f = Ts[g * 4 + q][rl];
            h[q]  = f2bf(f);
            lo[q] = f2bf(f - bf2f(h[q]));
        }
        ushort* d0 = Ycat + (size_t)(b * L_ + l0 + rl) * 2 * E_ + e0 + g * 4;
        *reinterpret_cast<uint2*>(d0)      = make_uint2((uint)h[0]  | ((uint)h[1]  << 16), (uint)h[2]  | ((uint)h[3]  << 16));
        *reinterpret_cast<uint2*>(d0 + E_) = make_uint2((uint)lo[0] | ((uint)lo[1] << 16), (uint)lo[2] | ((uint)lo[3] << 16));
    }
}

// Split-bf16 MFMA GEMM, templated BK (64/128), XOR-swizzled LDS both sides.
// Segments: A reads (hi,hi,lo), B reads (hi,lo,hi) -> Ahi*Bhi + Ahi*Blo + Alo*Bhi.
// 4 waves 2x2; wave-tile (BM/2)x(BN/2); frags 16x16x32; K order independent of BK.
// MODE 0: C[m*Ncols+n]; MODE 1: C[((b*E+e)<<11)+l]; MODE 2: MODE1+softplus(v+bias[e]);
// MODE 3: params epilogue — fp32 C cols [80,96) + hi|lo bf16 of cols [0,64) into P2.
template<int BM, int BN, int BK, int MODE>
__global__ __launch_bounds__(256)
void mfma_gemm(const ushort* __restrict__ A, const ushort* __restrict__ Bm,
               const float* __restrict__ bias, ushort* __restrict__ P2,
               float* __restrict__ C, int Kd, int Ncols) {
    constexpr int WTM = BM / 2, WTN = BN / 2;
    constexpr int MI = WTM / 16, NJ = WTN / 16;
    constexpr int CPR = BK / 8;              // 16B chunks per LDS row
    constexpr int KS  = BK / 32;             // mfma k-steps per phase
    constexpr int RPW = 64 / CPR;            // rows staged per wave per group
    __shared__ ushort As[BM * BK];
    __shared__ ushort Bs[BN * BK];
    const int tid  = threadIdx.x;
    const int wave = tid >> 6, lane = tid & 63;
    const int m0 = blockIdx.x * BM, n0 = blockIdx.y * BN;
    const int wr = wave >> 1, wc = wave & 1;
    const int fr = lane & 15, fg = lane >> 4;
    const int kxor = (fr & 7) << 3;          // ds_read swizzle (shorts, chunk low-3 bits)
    const int pK = 2 * Kd;

    f32x4 acc[MI][NJ];
#pragma unroll
    for (int i = 0; i < MI; ++i)
#pragma unroll
        for (int j = 0; j < NJ; ++j) { f32x4 z = {0.f, 0.f, 0.f, 0.f}; acc[i][j] = z; }

    const int lrow = lane / CPR;             // 0..RPW-1
    const int lc   = lane % CPR;             // chunk idx in row

    const int KP = Kd / BK;                  // phases per segment
    for (int seg = 0; seg < 3; ++seg) {
        const int ao = (seg == 2) ? Kd : 0;  // A: hi,hi,lo
        const int bo = (seg == 1) ? Kd : 0;  // B: hi,lo,hi
        for (int tt = 0; tt < KP; ++tt) {
            const int ka = ao + tt * BK, kb = bo + tt * BK;
#pragma unroll
            for (int g = 0; g < BM / (4 * RPW); ++g) {
                const int srow = (wave * (BM / (4 * RPW)) + g) * RPW + lrow;
                const int sc = (lc & 8) | ((lc ^ (srow & 7)) & 7);   // inverse swizzle on source
                gload16(A + (size_t)(m0 + srow) * pK + ka + sc * 8, As + srow * BK + lc * 8);
            }
#pragma unroll
            for (int g = 0; g < BN / (4 * RPW); ++g) {
                const int srow = (wave * (BN / (4 * RPW)) + g) * RPW + lrow;
                const int sc = (lc & 8) | ((lc ^ (srow & 7)) & 7);
                gload16(Bm + (size_t)(n0 + srow) * pK + kb + sc * 8, Bs + srow * BK + lc * 8);
            }
            __syncthreads();

#pragma unroll
            for (int ks = 0; ks < KS; ++ks) {
                bf16x8 av[MI], bv[NJ];
#pragma unroll
                for (int i = 0; i < MI; ++i) {
                    const int row = wr * WTM + i * 16 + fr;
                    av[i] = *reinterpret_cast<const bf16x8*>(&As[row * BK + ((ks * 32 + fg * 8) ^ kxor)]);
                }
#pragma unroll
                for (int j = 0; j < NJ; ++j) {
                    const int row = wc * WTN + j * 16 + fr;
                    bv[j] = *reinterpret_cast<const bf16x8*>(&Bs[row * BK + ((ks * 32 + fg * 8) ^ kxor)]);
                }
#pragma unroll
                for (int i = 0; i < MI; ++i)
#pragma unroll
                    for (int j = 0; j < NJ; ++j)
                        acc[i][j] = __builtin_amdgcn_mfma_f32_16x16x32_bf16(av[i], bv[j], acc[i][j], 0, 0, 0);
            }
            __syncthreads();
        }
    }

    if constexpr (MODE == 0) {
#pragma unroll
        for (int i = 0; i < MI; ++i) {
            const int m = m0 + wr * WTM + i * 16 + fg * 4;
#pragma unroll
            for (int j = 0; j < NJ; ++j) {
                const int n = n0 + wc * WTN + j * 16 + fr;
#pragma unroll
                for (int r = 0; r < 4; ++r)
                    C[(size_t)(m + r) * Ncols + n] = acc[i][j][r];
            }
        }
    } else if constexpr (MODE == 3) {
#pragma unroll
        for (int i = 0; i < MI; ++i) {
            const int m = m0 + wr * WTM + i * 16 + fg * 4;
#pragma unroll
            for (int j = 0; j < NJ; ++j) {
                const int n = n0 + wc * WTN + j * 16 + fr;
#pragma unroll
                for (int r = 0; r < 4; ++r) {
                    const float v = acc[i][j][r];
                    const int mm = m + r;
                    if (n < 64) {
                        const ushort hh = f2bf(v);
                        P2[(size_t)mm * 128 + n]      = hh;
                        P2[(size_t)mm * 128 + 64 + n] = f2bf(v - bf2f(hh));
                    } else if (n >= 80 && n < 96) {
                        C[(size_t)mm * Ncols + n] = v;
                    }
                }
            }
        }
    } else {
        const int b  = n0 >> 11;
        const int lb = n0 - (b << 11);
#pragma unroll
        for (int i = 0; i < MI; ++i) {
            const int e = m0 + wr * WTM + i * 16 + fg * 4;
#pragma unroll
            for (int r = 0; r < 4; ++r) {
                const float bia = (MODE == 2) ? bias[e + r] : 0.0f;
                float* row = C + ((size_t)(b * E_ + e + r) << 11) + lb;
#pragma unroll
                for (int j = 0; j < NJ; ++j) {
                    float v = acc[i][j][r];
                    if constexpr (MODE == 2) v = softplusf(v + bia);
                    row[wc * WTN + j * 16 + fr] = v;
                }
            }
        }
    }
}

// depthwise causal conv (K=4) + silu; x [b,l,e] -> uT[b,e,l]
__global__ __launch_bounds__(256)
void conv_silu_kernel(const float* __restrict__ x, const float* __restrict__ cw,
                      float* __restrict__ uT) {
    __shared__ float Xt[67][65];
    const int e0 = blockIdx.x * 64;
    const int l0 = blockIdx.y * 64;
    const int b  = blockIdx.z;
    const int tid = threadIdx.x;
    for (int idx = tid; idx < 67 * 64; idx += 256) {
        const int row = idx >> 6, col = idx & 63;
        const int gl = l0 - 3 + row;
        Xt[row][col] = (gl >= 0) ? x[((size_t)b * L_ + gl) * E_ + e0 + col] : 0.0f;
    }
    __syncthreads();
    const int lL = tid & 63;
    const int w  = tid >> 6;
    for (int ee = w; ee < 64; ee += 4) {
        const int e = e0 + ee;
        const float w0 = cw[e*4+0], w1 = cw[e*4+1], w2 = cw[e*4+2], w3 = cw[e*4+3];
        const float v = w0*Xt[lL][ee] + w1*Xt[lL+1][ee] + w2*Xt[lL+2][ee] + w3*Xt[lL+3][ee];
        uT[((size_t)b * E_ + e) * L_ + l0 + lL] = siluf(v);
    }
}

// selective scan: one block (4 waves, 256 threads) per (b,e) channel; 8 steps/thread.
// H_0 = g_0; H_{l+1} = a_l H_l + g_l; output at l uses H_l.
// Hierarchical scan: per-thread chunk transform -> wave inclusive scan ->
// cross-wave combine via LDS -> per-thread exclusive prefix applied to g_0.
// LDS slot(l) = (l>>5)*33 + (l&31); outputs overwrite sz in place.
__global__ __launch_bounds__(256)
void scan_kernel(const float* __restrict__ dtT, const float* __restrict__ uT,
                 const float* __restrict__ zT, const float* __restrict__ params,
                 const float* __restrict__ A_log, const float* __restrict__ Dp,
                 float* __restrict__ ygT) {
    __shared__ float sdt[64 * 33];
    __shared__ float su [64 * 33];
    __shared__ float sz [64 * 33];
    __shared__ float wPs[4][N_];
    __shared__ float wLs[4][N_];
    const int c = blockIdx.x;
    const int b = c >> 10;
    const int e = c & (E_ - 1);
    const int tid  = threadIdx.x;
    const int wave = tid >> 6, lane = tid & 63;
    constexpr int CH = 8;
    constexpr float LOG2E = 1.44269504088896340736f;

    const float* dtp = dtT + ((size_t)b * E_ + e) * L_;
    const float* up  = uT  + ((size_t)b * E_ + e) * L_;
    const float* zp  = zT  + ((size_t)b * E_ + e) * L_;

    // ---- stage dt/u/z rows (coalesced 4KB/instr across block) ----
#pragma unroll
    for (int it = 0; it < 2; ++it) {
        const int l = (it * 256 + tid) * 4;
        const int slot = ((l >> 5) * 33) + (l & 31);
        float4 vd = *reinterpret_cast<const float4*>(dtp + l);
        float4 vu = *reinterpret_cast<const float4*>(up  + l);
        float4 vz = *reinterpret_cast<const float4*>(zp  + l);
        sdt[slot] = vd.x; sdt[slot+1] = vd.y; sdt[slot+2] = vd.z; sdt[slot+3] = vd.w;
        su [slot] = vu.x; su [slot+1] = vu.y; su [slot+2] = vu.z; su [slot+3] = vu.w;
        sz [slot] = vz.x; sz [slot+1] = vz.y; sz [slot+2] = vz.z; sz [slot+3] = vz.w;
    }

    float An2[N_], rA[N_];
    unsigned selm = 0;
#pragma unroll
    for (int n = 0; n < N_; ++n) {
        const float A = -expf(A_log[e * N_ + n]);
        An2[n] = A * LOG2E;
        if (fabsf(A) < 1e-5f) selm |= (1u << n);
        rA[n] = 1.0f / (A + 1e-10f);
    }
    const float Dv = Dp[e];
    __syncthreads();

    const int base = (tid >> 2) * 33 + (tid & 3) * 8;
    // seed inputs: read before any pass-2 overwrite happens anywhere
    const float d0 = sdt[0];
    const float u0 = su[0];

    // ---- pass 1: per-thread chunk transform T(x) = P*x + h ----
    float P[N_], h[N_];
#pragma unroll
    for (int n = 0; n < N_; ++n) { P[n] = 1.0f; h[n] = 0.0f; }
#pragma unroll
    for (int j = 0; j < CH; ++j) {
        const float d  = sdt[base + j];
        const float uu = su [base + j];
#pragma unroll
        for (int n = 0; n < N_; ++n) {
            const float at = __builtin_amdgcn_exp2f(d * An2[n]);
            const float bt = ((selm >> n) & 1u) ? d : (at - 1.0f) * rA[n];
            h[n] = fmaf(at, h[n], bt * uu);
            P[n] *= at;
        }
    }

    // ---- wave-level inclusive scan ----
#pragma unroll
    for (int off = 1; off < 64; off <<= 1) {
#pragma unroll
        for (int n = 0; n < N_; ++n) {
            const float Pp = __shfl_up(P[n], off);
            const float Lp = __shfl_up(h[n], off);
            if (lane >= off) {
                h[n] = fmaf(P[n], Lp, h[n]);
                P[n] *= Pp;
            }
        }
    }

    // wave totals to LDS
    if (lane == 63) {
#pragma unroll
        for (int n = 0; n < N_; ++n) { wPs[wave][n] = P[n]; wLs[wave][n] = h[n]; }
    }
    // within-wave exclusive prefix
    float cP[N_], cL[N_];
#pragma unroll
    for (int n = 0; n < N_; ++n) {
        cP[n] = __shfl_up(P[n], 1);
        cL[n] = __shfl_up(h[n], 1);
    }
    __syncthreads();

    // compose carry of previous waves, then seed H at chunk start
    float EP[N_], EL[N_];
#pragma unroll
    for (int n = 0; n < N_; ++n) { EP[n] = 1.0f; EL[n] = 0.0f; }
    for (int w2 = 0; w2 < wave; ++w2) {
#pragma unroll
        for (int n = 0; n < N_; ++n) {
            EL[n] = fmaf(wPs[w2][n], EL[n], wLs[w2][n]);
            EP[n] *= wPs[w2][n];
        }
    }
#pragma unroll
    for (int n = 0; n < N_; ++n) {
        const float pl = (lane == 0) ? 1.0f : cP[n];
        const float ll = (lane == 0) ? 0.0f : cL[n];
        const float fP = pl * EP[n];
        const float fL = fmaf(pl, EL[n], ll);
        const float at0 = __builtin_amdgcn_exp2f(d0 * An2[n]);
        const float bt0 = ((selm >> n) & 1u) ? d0 : (at0 - 1.0f) * rA[n];
        const float g0  = bt0 * u0;
        h[n] = fmaf(fP, g0, fL);      // identity prefix for global thread 0 -> g0
    }

    // ---- pass 2: emit outputs; overwrite sz slots in place ----
    const float* crow = params + (size_t)b * L_ * PWP + 80;   // C_proj cols [80,96)
    const int l0 = tid * CH;
#pragma unroll
    for (int j = 0; j < CH; ++j) {
        const float d  = sdt[base + j];
        const float uu = su [base + j];
        const float zv = sz [base + j];
        float Cv[N_];
        const float4* Cp4 = reinterpret_cast<const float4*>(crow + (size_t)(l0 + j) * PWP);
#pragma unroll
        for (int t = 0; t < N_ / 4; ++t)
            *reinterpret_cast<float4*>(Cv + t * 4) = Cp4[t];
        float y = 0.0f;
#pragma unroll
        for (int n = 0; n < N_; ++n) y = fmaf(Cv[n], h[n], y);
        const float outv = (y + uu * Dv) * siluf(zv);
        if (j < CH - 1) {   // final update is dead (next chunk uses scan carry)
#pragma unroll
            for (int n = 0; n < N_; ++n) {
                const float at = __builtin_amdgcn_exp2f(d * An2[n]);
                const float bt = ((selm >> n) & 1u) ? d : (at - 1.0f) * rA[n];
                h[n] = fmaf(at, h[n], bt * uu);
            }
        }
        sz[base + j] = outv;
    }
    __syncthreads();

    // ---- coalesced store of outputs ----
    float* yp = ygT + ((size_t)b * E_ + e) * L_;
#pragma unroll
    for (int it = 0; it < 2; ++it) {
        const int l = (it * 256 + tid) * 4;
        const int slot = ((l >> 5) * 33) + (l & 31);
        float4 o;
        o.x = sz[slot]; o.y = sz[slot+1]; o.z = sz[slot+2]; o.w = sz[slot+3];
        *reinterpret_cast<float4*>(yp + l) = o;
    }
}

extern "C" void kernel_launch(void* const* d_in, const int* in_sizes, int n_in,
                              void* d_out, int out_size, void* d_ws, size_t ws_size,
                              hipStream_t stream) {
    const float* x     = (const float*)d_in[0];
    const float* W_z   = (const float*)d_in[1];
    const float* W_p   = (const float*)d_in[2];
    const float* cw    = (const float*)d_in[3];
    const float* W_dt  = (const float*)d_in[4];
    const float* b_dt  = (const float*)d_in[5];
    const float* A_log = (const float*)d_in[6];
    const float* Dp    = (const float*)d_in[7];
    const float* W_out = (const float*)d_in[8];
    float* out = (float*)d_out;

    char* w = (char*)d_ws;
    ushort* Xcat   = (ushort*)(w);               // [4096][2048]  16.78 MB
    ushort* Wzcat  = (ushort*)(w + 16777216);    // [1024][2048]   4.19 MB
    ushort* Wpcat  = (ushort*)(w + 20971520);    // [128][2048]    0.52 MB
    ushort* Wdtcat = (ushort*)(w + 21495808);    // [1024][128]    0.26 MB
    ushort* Pcat   = (ushort*)(w + 21757952);    // [4096][128]    1.05 MB
    float*  params = (float*)(w + 22806528);     // [4096][128]    2.10 MB
    float*  zT     = (float*)(w + 24903680);     // 16.78 MB
    float*  dtT    = (float*)(w + 41680896);     // 16.78 MB
    float*  uT     = (float*)(w + 58458112);     // 16.78 MB
    float*  ygT    = (float*)(w + 75235328);     // 16.78 MB
    ushort* Ycat   = Xcat;                       // alias (Xcat dead by then)
    ushort* Wocat  = Wzcat;                      // alias (Wzcat dead by then)

    // x split + merged weight splits
    split_rm<<<4096, 256, 0, stream>>>(x, E_, BL_, Xcat, E_, BL_ * E_ / 4);
    split_w3<<<dim3(1024, 3), 256, 0, stream>>>(W_z, W_p, W_dt, Wzcat, Wpcat, Wdtcat);
    // z = x @ W_z^T -> zT[b,e,l]   (A = W_z rows e, B = x rows bl)
    mfma_gemm<128,64,128,1><<<dim3(E_ / 128, BL_ / 64), 256, 0, stream>>>(
        Wzcat, Xcat, nullptr, nullptr, zT, E_, 0);
    // params = x @ W_p^T: fp32 C_proj cols [80,96) + bf16 hi|lo dt_unproj -> Pcat
    mfma_gemm<64,64,128,3><<<dim3(BL_ / 64, 2), 256, 0, stream>>>(
        Xcat, Wpcat, nullptr, Pcat, params, E_, PWP);
    // dt = softplus(dt_unproj @ W_dt^T + b_dt) -> dtT[b,e,l]
    mfma_gemm<128,64,64,2><<<dim3(E_ / 128, BL_ / 64), 256, 0, stream>>>(
        Wdtcat, Pcat, b_dt, nullptr, dtT, R_, 0);
    // conv + silu -> uT
    conv_silu_kernel<<<dim3(E_ / 64, L_ / 64, B_), 256, 0, stream>>>(x, cw, uT);
    // scan -> ygT
    scan_kernel<<<B_ * E_, 256, 0, stream>>>(dtT, uT, zT, params, A_log, Dp, ygT);
    // yg split (transpose) + W_out split
    split_tr<<<dim3(E_ / 64, L_ / 64, B_), 256, 0, stream>>>(ygT, Ycat);
    split_rm<<<1024, 256, 0, stream>>>(W_out, E_, E_, Wocat, E_, E_ * E_ / 4);
    // out = yg @ W_out^T
    mfma_gemm<128,64,128,0><<<dim3(BL_ / 128, E_ / 64), 256, 0, stream>>>(
        Ycat, Wocat, nullptr, nullptr, out, E_, E_);
}